// Round 3
// baseline (824.418 us; speedup 1.0000x reference)
//
#include <hip/hip_runtime.h>
#include <hip/hip_bf16.h>

#define N_NODES 100000
#define N_EDGES 800000
#define EPS 1e-5f

typedef __attribute__((ext_vector_type(8))) short short8;
typedef __attribute__((ext_vector_type(4))) float floatx4;

__device__ __forceinline__ unsigned short f2b(float f) {
    unsigned int u = __float_as_uint(f);
    u = (u + 0x7fffu + ((u >> 16) & 1u)) >> 16;   // round-to-nearest-even
    return (unsigned short)u;
}
__device__ __forceinline__ float blo(unsigned int u) { return __uint_as_float(u << 16); }
__device__ __forceinline__ float bhi(unsigned int u) { return __uint_as_float(u & 0xffff0000u); }

// ---------------- elementwise convert fp32 -> bf16 (x input) ----------------
__global__ void cvt_f32_bf16(const float* __restrict__ x, unsigned short* __restrict__ o, int n4) {
    int i = blockIdx.x * blockDim.x + threadIdx.x;
    if (i >= n4) return;
    float4 v = ((const float4*)x)[i];
    ushort4 r;
    r.x = f2b(v.x); r.y = f2b(v.y); r.z = f2b(v.z); r.w = f2b(v.w);
    ((ushort4*)o)[i] = r;
}

// ---------------- pack [Wl;Wr] (K=256 x Hreal) into MFMA B-fragment order ----
__global__ void pack_w(const float* __restrict__ Wl, const float* __restrict__ Wr,
                       unsigned short* __restrict__ out, int Hreal, int NCT) {
    int tid = blockIdx.x * blockDim.x + threadIdx.x;
    int total = NCT * 8 * 64 * 8;
    if (tid >= total) return;
    int i = tid & 7;
    int lane = (tid >> 3) & 63;
    int q = tid >> 9;
    int c = q % NCT;
    int t = q / NCT;
    int k = t * 32 + (lane >> 4) * 8 + i;
    int n = c * 16 + (lane & 15);
    float v = 0.f;
    if (n < Hreal) v = (k < 128) ? Wl[k * Hreal + n] : Wr[(k - 128) * Hreal + n];
    out[tid] = f2b(v);
}

// ---------------- CSR build ----------------
__global__ void hist_k(const int* __restrict__ dst, unsigned int* __restrict__ cnt) {
    int e = blockIdx.x * blockDim.x + threadIdx.x;
    if (e < N_EDGES) atomicAdd(&cnt[dst[e]], 1u);
}

__global__ void scan1(const unsigned int* __restrict__ cnt, unsigned int* __restrict__ rowptr,
                      unsigned int* __restrict__ bsum) {
    __shared__ unsigned int sh[256];
    int t = threadIdx.x;
    int i = blockIdx.x * 256 + t;
    unsigned int v = (i < N_NODES) ? cnt[i] : 0u;
    sh[t] = v; __syncthreads();
    for (int off = 1; off < 256; off <<= 1) {
        unsigned int add = (t >= off) ? sh[t - off] : 0u;
        __syncthreads();
        sh[t] += add;
        __syncthreads();
    }
    if (i < N_NODES) rowptr[i] = sh[t] - v;  // exclusive within block
    if (t == 255) bsum[blockIdx.x] = sh[255];
}

__global__ void scan2(const unsigned int* __restrict__ bsum, unsigned int* __restrict__ boff, int nb) {
    __shared__ unsigned int sh[512];
    int t = threadIdx.x;
    unsigned int v = (t < nb) ? bsum[t] : 0u;
    sh[t] = v; __syncthreads();
    for (int off = 1; off < 512; off <<= 1) {
        unsigned int add = (t >= off) ? sh[t - off] : 0u;
        __syncthreads();
        sh[t] += add;
        __syncthreads();
    }
    if (t < nb) boff[t] = sh[t] - v;
}

__global__ void scan3(unsigned int* __restrict__ rowptr, const unsigned int* __restrict__ boff,
                      unsigned int* __restrict__ cursor) {
    int i = blockIdx.x * 256 + threadIdx.x;
    if (i < N_NODES) {
        unsigned int r = rowptr[i] + boff[blockIdx.x];
        rowptr[i] = r;
        cursor[i] = r;
    }
    if (i == N_NODES) rowptr[N_NODES] = N_EDGES;
}

__global__ void scatter_k(const int* __restrict__ src, const int* __restrict__ dst,
                          unsigned int* __restrict__ cursor, int* __restrict__ srclist) {
    int e = blockIdx.x * blockDim.x + threadIdx.x;
    if (e < N_EDGES) {
        unsigned int p = atomicAdd(&cursor[dst[e]], 1u);
        srclist[p] = src[e];
    }
}

// ---------------- mean aggregation ------------------------------------------
// One wave per node; lanes = 4 groups x 16. Group g gathers a full neighbor
// row with dwordx4 (1 KiB / instruction, 4 edges in parallel), unrolled x2
// (8 rows in flight). Cross-group butterfly reduce at the end.
__global__ void __launch_bounds__(256) agg_k(const unsigned short* __restrict__ h,
                                             const unsigned int* __restrict__ rowptr,
                                             const int* __restrict__ srclist,
                                             unsigned short* __restrict__ mean) {
    int tid = blockIdx.x * 256 + threadIdx.x;
    int node = tid >> 6;
    int lane = tid & 63;
    if (node >= N_NODES) return;
    int g = lane >> 4, l = lane & 15;
    unsigned int b = rowptr[node], e = rowptr[node + 1];
    const uint4* hp = (const uint4*)h;
    float a0 = 0.f, a1 = 0.f, a2 = 0.f, a3 = 0.f, a4 = 0.f, a5 = 0.f, a6 = 0.f, a7 = 0.f;
    float b0 = 0.f, b1 = 0.f, b2 = 0.f, b3 = 0.f, b4 = 0.f, b5 = 0.f, b6 = 0.f, b7 = 0.f;
    unsigned int p = b;
    for (; p + 8 <= e; p += 8) {
        int s0 = srclist[p + g];
        int s1 = srclist[p + 4 + g];
        uint4 u0 = hp[(size_t)s0 * 16 + l];
        uint4 u1 = hp[(size_t)s1 * 16 + l];
        a0 += blo(u0.x); a1 += bhi(u0.x); a2 += blo(u0.y); a3 += bhi(u0.y);
        a4 += blo(u0.z); a5 += bhi(u0.z); a6 += blo(u0.w); a7 += bhi(u0.w);
        b0 += blo(u1.x); b1 += bhi(u1.x); b2 += blo(u1.y); b3 += bhi(u1.y);
        b4 += blo(u1.z); b5 += bhi(u1.z); b6 += blo(u1.w); b7 += bhi(u1.w);
    }
    if (p + 4 <= e) {
        int s0 = srclist[p + g];
        uint4 u0 = hp[(size_t)s0 * 16 + l];
        a0 += blo(u0.x); a1 += bhi(u0.x); a2 += blo(u0.y); a3 += bhi(u0.y);
        a4 += blo(u0.z); a5 += bhi(u0.z); a6 += blo(u0.w); a7 += bhi(u0.w);
        p += 4;
    }
    unsigned int rem = e - p;  // 0..3
    if ((unsigned int)g < rem) {
        int s1 = srclist[p + g];
        uint4 u1 = hp[(size_t)s1 * 16 + l];
        b0 += blo(u1.x); b1 += bhi(u1.x); b2 += blo(u1.y); b3 += bhi(u1.y);
        b4 += blo(u1.z); b5 += bhi(u1.z); b6 += blo(u1.w); b7 += bhi(u1.w);
    }
    unsigned int deg = e - b;
    float r = 1.0f / (float)(deg > 1u ? deg : 1u);
    float f0 = a0 + b0, f1 = a1 + b1, f2 = a2 + b2, f3 = a3 + b3;
    float f4 = a4 + b4, f5 = a5 + b5, f6 = a6 + b6, f7 = a7 + b7;
    f0 += __shfl_xor(f0, 16); f0 += __shfl_xor(f0, 32);
    f1 += __shfl_xor(f1, 16); f1 += __shfl_xor(f1, 32);
    f2 += __shfl_xor(f2, 16); f2 += __shfl_xor(f2, 32);
    f3 += __shfl_xor(f3, 16); f3 += __shfl_xor(f3, 32);
    f4 += __shfl_xor(f4, 16); f4 += __shfl_xor(f4, 32);
    f5 += __shfl_xor(f5, 16); f5 += __shfl_xor(f5, 32);
    f6 += __shfl_xor(f6, 16); f6 += __shfl_xor(f6, 32);
    f7 += __shfl_xor(f7, 16); f7 += __shfl_xor(f7, 32);
    if (g == 0) {
        uint4 o;
        o.x = (unsigned int)f2b(f0 * r) | ((unsigned int)f2b(f1 * r) << 16);
        o.y = (unsigned int)f2b(f2 * r) | ((unsigned int)f2b(f3 * r) << 16);
        o.z = (unsigned int)f2b(f4 * r) | ((unsigned int)f2b(f5 * r) << 16);
        o.w = (unsigned int)f2b(f6 * r) | ((unsigned int)f2b(f7 * r) << 16);
        ((uint4*)mean)[(size_t)node * 16 + l] = o;
    }
}

// ---------------- GEMM: C[N x HSTORE] = [mean|h] @ packedB, bf16 MFMA --------
// STATS: also emit per-block column sum/sumsq partials (BN fused, no C re-read).
template <int NCT, int HSTORE, bool BIAS, bool STATS>
__global__ void __launch_bounds__(256) gemm_k(const unsigned short* __restrict__ meanb,
                                              const unsigned short* __restrict__ hb,
                                              const unsigned short* __restrict__ Bp,
                                              const float* __restrict__ bias,
                                              float* __restrict__ out,
                                              float* __restrict__ partials) {
    __shared__ float lds_s[128];
    __shared__ float lds_s2[128];
    int wave = threadIdx.x >> 6;
    int lane = threadIdx.x & 63;
    int quad = lane >> 4;
    int l15 = lane & 15;
    int rowbase = blockIdx.x * 128 + wave * 32;

    if (STATS) {
        if (threadIdx.x < 128) { lds_s[threadIdx.x] = 0.f; lds_s2[threadIdx.x] = 0.f; }
        __syncthreads();
    }

    floatx4 acc[2][NCT];
#pragma unroll
    for (int w = 0; w < 2; w++)
#pragma unroll
        for (int c = 0; c < NCT; c++) acc[w][c] = (floatx4){0.f, 0.f, 0.f, 0.f};

    int r0 = rowbase + l15;       if (r0 > N_NODES - 1) r0 = N_NODES - 1;
    int r1 = rowbase + 16 + l15;  if (r1 > N_NODES - 1) r1 = N_NODES - 1;

#pragma unroll
    for (int t = 0; t < 8; t++) {
        const unsigned short* base = (t < 4) ? meanb : hb;
        int koff = (t & 3) * 32 + quad * 8;
        short8 a0 = *(const short8*)(base + (size_t)r0 * 128 + koff);
        short8 a1 = *(const short8*)(base + (size_t)r1 * 128 + koff);
#pragma unroll
        for (int c = 0; c < NCT; c++) {
            short8 bf = *(const short8*)(Bp + ((size_t)(t * NCT + c) * 64 + lane) * 8);
            acc[0][c] = __builtin_amdgcn_mfma_f32_16x16x32_bf16(a0, bf, acc[0][c], 0, 0, 0);
            acc[1][c] = __builtin_amdgcn_mfma_f32_16x16x32_bf16(a1, bf, acc[1][c], 0, 0, 0);
        }
    }

#pragma unroll
    for (int c = 0; c < NCT; c++) {
        int col = c * 16 + l15;
        float s = 0.f, s2 = 0.f;
        if (!(NCT * 16 > HSTORE && col >= HSTORE)) {
#pragma unroll
            for (int w = 0; w < 2; w++) {
#pragma unroll
                for (int r = 0; r < 4; r++) {
                    int row = rowbase + w * 16 + quad * 4 + r;
                    if (row < N_NODES) {
                        float v = acc[w][c][r];
                        if (BIAS) v += bias[col];
                        out[(size_t)row * HSTORE + col] = v;
                        if (STATS) { s += v; s2 += v * v; }
                    }
                }
            }
        }
        if (STATS) {
            s += __shfl_xor(s, 16);  s += __shfl_xor(s, 32);
            s2 += __shfl_xor(s2, 16); s2 += __shfl_xor(s2, 32);
            if (quad == 0) {
                atomicAdd(&lds_s[col], s);
                atomicAdd(&lds_s2[col], s2);
            }
        }
    }

    if (STATS) {
        __syncthreads();
        if (threadIdx.x < 128) {
            partials[(size_t)blockIdx.x * 256 + threadIdx.x] = lds_s[threadIdx.x];
            partials[(size_t)blockIdx.x * 256 + 128 + threadIdx.x] = lds_s2[threadIdx.x];
        }
    }
}

// ---------------- BN finalize from per-block partials ------------------------
__global__ void bn_finalize2(const float* __restrict__ partials, int nblocks,
                             const float* __restrict__ g, const float* __restrict__ be,
                             float* __restrict__ sc, float* __restrict__ sh) {
    __shared__ float lds[256];
    int t = threadIdx.x;
    float s = 0.f;
    for (int i = 0; i < nblocks; i++) s += partials[(size_t)i * 256 + t];
    lds[t] = s;
    __syncthreads();
    if (t < 128) {
        float inv_n = 1.0f / (float)N_NODES;
        float mu = lds[t] * inv_n;
        float var = lds[128 + t] * inv_n - mu * mu;
        float sf = g[t] * rsqrtf(var + EPS);
        sc[t] = sf;
        sh[t] = be[t] - mu * sf;
    }
}

__global__ void bn_apply(const float* __restrict__ C, const float* __restrict__ sc,
                         const float* __restrict__ sh, unsigned short* __restrict__ ho) {
    int i = blockIdx.x * 256 + threadIdx.x;  // one float4 per thread
    if (i >= N_NODES * 32) return;
    float4 v = ((const float4*)C)[i];
    int c0 = (i * 4) & 127;
    float a = fmaxf(0.f, v.x * sc[c0] + sh[c0]);
    float b = fmaxf(0.f, v.y * sc[c0 + 1] + sh[c0 + 1]);
    float c = fmaxf(0.f, v.z * sc[c0 + 2] + sh[c0 + 2]);
    float d = fmaxf(0.f, v.w * sc[c0 + 3] + sh[c0 + 3]);
    ushort4 o;
    o.x = f2b(a); o.y = f2b(b); o.z = f2b(c); o.w = f2b(d);
    ((ushort4*)ho)[i] = o;
}

// ---------------- host ----------------
extern "C" void kernel_launch(void* const* d_in, const int* in_sizes, int n_in,
                              void* d_out, int out_size, void* d_ws, size_t ws_size,
                              hipStream_t stream) {
    const float* x   = (const float*)d_in[0];
    const int* ei    = (const int*)d_in[1];     // [2, E] int32: row 0 = src, row 1 = dst
    const float* Wl0 = (const float*)d_in[2];
    const float* Wr0 = (const float*)d_in[3];
    const float* Wl1 = (const float*)d_in[4];
    const float* Wr1 = (const float*)d_in[5];
    const float* Wl2 = (const float*)d_in[6];
    const float* Wr2 = (const float*)d_in[7];
    const float* b2  = (const float*)d_in[8];
    const float* g0  = (const float*)d_in[9];
    const float* be0 = (const float*)d_in[10];
    const float* g1  = (const float*)d_in[11];
    const float* be1 = (const float*)d_in[12];

    char* ws = (char*)d_ws;
    size_t off = 0;
    auto alloc = [&](size_t bytes) -> void* {
        void* p = ws + off;
        off += (bytes + 4095) & ~(size_t)4095;
        return p;
    };

    const size_t NB16 = (size_t)N_NODES * 128 * 2;  // 25.6 MB bf16 feature buffer
    unsigned short* xb   = (unsigned short*)alloc(NB16);   // x in bf16; reused as h2
    unsigned short* h1   = (unsigned short*)alloc(NB16);
    unsigned short* mean = (unsigned short*)alloc(NB16);
    float* C             = (float*)alloc((size_t)N_NODES * 128 * 4);
    unsigned int* cnt    = (unsigned int*)alloc((size_t)N_NODES * 4);
    unsigned int* rowptr = (unsigned int*)alloc((size_t)(N_NODES + 1) * 4);
    unsigned int* cursor = (unsigned int*)alloc((size_t)N_NODES * 4);
    int* srclist         = (int*)alloc((size_t)N_EDGES * 4);
    unsigned int* bsum   = (unsigned int*)alloc(512 * 4);
    unsigned int* boff   = (unsigned int*)alloc(512 * 4);
    float* partials      = (float*)alloc((size_t)782 * 256 * 4);
    float* sc            = (float*)alloc(128 * 4);
    float* sh            = (float*)alloc(128 * 4);
    unsigned short* W0p  = (unsigned short*)alloc(8 * 8 * 64 * 8 * 2);
    unsigned short* W1p  = (unsigned short*)alloc(8 * 8 * 64 * 8 * 2);
    unsigned short* W2p  = (unsigned short*)alloc(3 * 8 * 64 * 8 * 2);
    unsigned short* h2   = xb;  // alias: xb dead after layer-0 GEMM

    const int* srcp = ei;
    const int* dstp = ei + N_EDGES;

    // ---- prep ----
    hipMemsetAsync(cnt, 0, (size_t)N_NODES * 4, stream);
    cvt_f32_bf16<<<12500, 256, 0, stream>>>(x, xb, N_NODES * 32);
    pack_w<<<(8 * 4096 + 255) / 256, 256, 0, stream>>>(Wl0, Wr0, W0p, 128, 8);
    pack_w<<<(8 * 4096 + 255) / 256, 256, 0, stream>>>(Wl1, Wr1, W1p, 128, 8);
    pack_w<<<(3 * 4096 + 255) / 256, 256, 0, stream>>>(Wl2, Wr2, W2p, 40, 3);

    // ---- CSR ----
    hist_k<<<(N_EDGES + 255) / 256, 256, 0, stream>>>(dstp, cnt);
    scan1<<<391, 256, 0, stream>>>(cnt, rowptr, bsum);
    scan2<<<1, 512, 0, stream>>>(bsum, boff, 391);
    scan3<<<391, 256, 0, stream>>>(rowptr, boff, cursor);
    scatter_k<<<(N_EDGES + 255) / 256, 256, 0, stream>>>(srcp, dstp, cursor, srclist);

    // ---- layer 0 ----
    agg_k<<<25000, 256, 0, stream>>>(xb, rowptr, srclist, mean);
    gemm_k<8, 128, false, true><<<782, 256, 0, stream>>>(mean, xb, W0p, nullptr, C, partials);
    bn_finalize2<<<1, 256, 0, stream>>>(partials, 782, g0, be0, sc, sh);
    bn_apply<<<12500, 256, 0, stream>>>(C, sc, sh, h1);

    // ---- layer 1 ----
    agg_k<<<25000, 256, 0, stream>>>(h1, rowptr, srclist, mean);
    gemm_k<8, 128, false, true><<<782, 256, 0, stream>>>(mean, h1, W1p, nullptr, C, partials);
    bn_finalize2<<<1, 256, 0, stream>>>(partials, 782, g1, be1, sc, sh);
    bn_apply<<<12500, 256, 0, stream>>>(C, sc, sh, h2);

    // ---- layer 2 (writes d_out, fp32 [N,40]) ----
    agg_k<<<25000, 256, 0, stream>>>(h2, rowptr, srclist, mean);
    gemm_k<3, 40, true, false><<<782, 256, 0, stream>>>(mean, h2, W2p, b2, (float*)d_out, nullptr);

    (void)in_sizes; (void)n_in; (void)out_size; (void)ws_size;
}

// Round 4
// 502.024 us; speedup vs baseline: 1.6422x; 1.6422x over previous
//
#include <hip/hip_runtime.h>
#include <hip/hip_bf16.h>

#define N_NODES 100000
#define N_EDGES 800000
#define EPS 1e-5f

typedef __attribute__((ext_vector_type(8))) short short8;
typedef __attribute__((ext_vector_type(4))) float floatx4;

__device__ __forceinline__ unsigned short f2b(float f) {
    unsigned int u = __float_as_uint(f);
    u = (u + 0x7fffu + ((u >> 16) & 1u)) >> 16;   // round-to-nearest-even
    return (unsigned short)u;
}
__device__ __forceinline__ float blo(unsigned int u) { return __uint_as_float(u << 16); }
__device__ __forceinline__ float bhi(unsigned int u) { return __uint_as_float(u & 0xffff0000u); }

// ---------------- elementwise convert fp32 -> bf16 (x input) ----------------
__global__ void cvt_f32_bf16(const float* __restrict__ x, unsigned short* __restrict__ o, int n4) {
    int i = blockIdx.x * blockDim.x + threadIdx.x;
    if (i >= n4) return;
    float4 v = ((const float4*)x)[i];
    ushort4 r;
    r.x = f2b(v.x); r.y = f2b(v.y); r.z = f2b(v.z); r.w = f2b(v.w);
    ((ushort4*)o)[i] = r;
}

// ---------------- pack [Wl;Wr] (K=256 x Hreal) into MFMA B-fragment order ----
__global__ void pack_w(const float* __restrict__ Wl, const float* __restrict__ Wr,
                       unsigned short* __restrict__ out, int Hreal, int NCT) {
    int tid = blockIdx.x * blockDim.x + threadIdx.x;
    int total = NCT * 8 * 64 * 8;
    if (tid >= total) return;
    int i = tid & 7;
    int lane = (tid >> 3) & 63;
    int q = tid >> 9;
    int c = q % NCT;
    int t = q / NCT;
    int k = t * 32 + (lane >> 4) * 8 + i;
    int n = c * 16 + (lane & 15);
    float v = 0.f;
    if (n < Hreal) v = (k < 128) ? Wl[k * Hreal + n] : Wr[(k - 128) * Hreal + n];
    out[tid] = f2b(v);
}

// ---------------- CSR build ----------------
__global__ void hist_k(const int* __restrict__ dst, unsigned int* __restrict__ cnt) {
    int e = blockIdx.x * blockDim.x + threadIdx.x;
    if (e < N_EDGES) atomicAdd(&cnt[dst[e]], 1u);
}

__global__ void scan1(const unsigned int* __restrict__ cnt, unsigned int* __restrict__ rowptr,
                      unsigned int* __restrict__ bsum) {
    __shared__ unsigned int sh[256];
    int t = threadIdx.x;
    int i = blockIdx.x * 256 + t;
    unsigned int v = (i < N_NODES) ? cnt[i] : 0u;
    sh[t] = v; __syncthreads();
    for (int off = 1; off < 256; off <<= 1) {
        unsigned int add = (t >= off) ? sh[t - off] : 0u;
        __syncthreads();
        sh[t] += add;
        __syncthreads();
    }
    if (i < N_NODES) rowptr[i] = sh[t] - v;  // exclusive within block
    if (t == 255) bsum[blockIdx.x] = sh[255];
}

__global__ void scan2(const unsigned int* __restrict__ bsum, unsigned int* __restrict__ boff, int nb) {
    __shared__ unsigned int sh[512];
    int t = threadIdx.x;
    unsigned int v = (t < nb) ? bsum[t] : 0u;
    sh[t] = v; __syncthreads();
    for (int off = 1; off < 512; off <<= 1) {
        unsigned int add = (t >= off) ? sh[t - off] : 0u;
        __syncthreads();
        sh[t] += add;
        __syncthreads();
    }
    if (t < nb) boff[t] = sh[t] - v;
}

__global__ void scan3(unsigned int* __restrict__ rowptr, const unsigned int* __restrict__ boff,
                      unsigned int* __restrict__ cursor) {
    int i = blockIdx.x * 256 + threadIdx.x;
    if (i < N_NODES) {
        unsigned int r = rowptr[i] + boff[blockIdx.x];
        rowptr[i] = r;
        cursor[i] = r;
    }
    if (i == N_NODES) rowptr[N_NODES] = N_EDGES;
}

__global__ void scatter_k(const int* __restrict__ src, const int* __restrict__ dst,
                          unsigned int* __restrict__ cursor, int* __restrict__ srclist) {
    int e = blockIdx.x * blockDim.x + threadIdx.x;
    if (e < N_EDGES) {
        unsigned int p = atomicAdd(&cursor[dst[e]], 1u);
        srclist[p] = src[e];
    }
}

// ---------------- mean aggregation ------------------------------------------
// One wave per node; lanes = 4 groups x 16. Group g gathers a full neighbor
// row with dwordx4 (1 KiB / instruction, 4 edges in parallel), unrolled x2
// (8 rows in flight). Cross-group butterfly reduce at the end.
__global__ void __launch_bounds__(256) agg_k(const unsigned short* __restrict__ h,
                                             const unsigned int* __restrict__ rowptr,
                                             const int* __restrict__ srclist,
                                             unsigned short* __restrict__ mean) {
    int tid = blockIdx.x * 256 + threadIdx.x;
    int node = tid >> 6;
    int lane = tid & 63;
    if (node >= N_NODES) return;
    int g = lane >> 4, l = lane & 15;
    unsigned int b = rowptr[node], e = rowptr[node + 1];
    const uint4* hp = (const uint4*)h;
    float a0 = 0.f, a1 = 0.f, a2 = 0.f, a3 = 0.f, a4 = 0.f, a5 = 0.f, a6 = 0.f, a7 = 0.f;
    float b0 = 0.f, b1 = 0.f, b2 = 0.f, b3 = 0.f, b4 = 0.f, b5 = 0.f, b6 = 0.f, b7 = 0.f;
    unsigned int p = b;
    for (; p + 8 <= e; p += 8) {
        int s0 = srclist[p + g];
        int s1 = srclist[p + 4 + g];
        uint4 u0 = hp[(size_t)s0 * 16 + l];
        uint4 u1 = hp[(size_t)s1 * 16 + l];
        a0 += blo(u0.x); a1 += bhi(u0.x); a2 += blo(u0.y); a3 += bhi(u0.y);
        a4 += blo(u0.z); a5 += bhi(u0.z); a6 += blo(u0.w); a7 += bhi(u0.w);
        b0 += blo(u1.x); b1 += bhi(u1.x); b2 += blo(u1.y); b3 += bhi(u1.y);
        b4 += blo(u1.z); b5 += bhi(u1.z); b6 += blo(u1.w); b7 += bhi(u1.w);
    }
    if (p + 4 <= e) {
        int s0 = srclist[p + g];
        uint4 u0 = hp[(size_t)s0 * 16 + l];
        a0 += blo(u0.x); a1 += bhi(u0.x); a2 += blo(u0.y); a3 += bhi(u0.y);
        a4 += blo(u0.z); a5 += bhi(u0.z); a6 += blo(u0.w); a7 += bhi(u0.w);
        p += 4;
    }
    unsigned int rem = e - p;  // 0..3
    if ((unsigned int)g < rem) {
        int s1 = srclist[p + g];
        uint4 u1 = hp[(size_t)s1 * 16 + l];
        b0 += blo(u1.x); b1 += bhi(u1.x); b2 += blo(u1.y); b3 += bhi(u1.y);
        b4 += blo(u1.z); b5 += bhi(u1.z); b6 += blo(u1.w); b7 += bhi(u1.w);
    }
    unsigned int deg = e - b;
    float r = 1.0f / (float)(deg > 1u ? deg : 1u);
    float f0 = a0 + b0, f1 = a1 + b1, f2 = a2 + b2, f3 = a3 + b3;
    float f4 = a4 + b4, f5 = a5 + b5, f6 = a6 + b6, f7 = a7 + b7;
    f0 += __shfl_xor(f0, 16); f0 += __shfl_xor(f0, 32);
    f1 += __shfl_xor(f1, 16); f1 += __shfl_xor(f1, 32);
    f2 += __shfl_xor(f2, 16); f2 += __shfl_xor(f2, 32);
    f3 += __shfl_xor(f3, 16); f3 += __shfl_xor(f3, 32);
    f4 += __shfl_xor(f4, 16); f4 += __shfl_xor(f4, 32);
    f5 += __shfl_xor(f5, 16); f5 += __shfl_xor(f5, 32);
    f6 += __shfl_xor(f6, 16); f6 += __shfl_xor(f6, 32);
    f7 += __shfl_xor(f7, 16); f7 += __shfl_xor(f7, 32);
    if (g == 0) {
        uint4 o;
        o.x = (unsigned int)f2b(f0 * r) | ((unsigned int)f2b(f1 * r) << 16);
        o.y = (unsigned int)f2b(f2 * r) | ((unsigned int)f2b(f3 * r) << 16);
        o.z = (unsigned int)f2b(f4 * r) | ((unsigned int)f2b(f5 * r) << 16);
        o.w = (unsigned int)f2b(f6 * r) | ((unsigned int)f2b(f7 * r) << 16);
        ((uint4*)mean)[(size_t)node * 16 + l] = o;
    }
}

// ---------------- GEMM: C[N x HSTORE] = [mean|h] @ packedB, bf16 MFMA --------
// STATS: fused BN stats -> LDS block reduce -> device atomicAdd to sums[256].
// (R3 post-mortem: per-block partials + single-block serial reduce was 183 us;
//  782 blocks x 256 atomics to a 1 KB array is the R1 bn_stats profile, ~free.)
template <int NCT, int HSTORE, bool BIAS, bool STATS>
__global__ void __launch_bounds__(256) gemm_k(const unsigned short* __restrict__ meanb,
                                              const unsigned short* __restrict__ hb,
                                              const unsigned short* __restrict__ Bp,
                                              const float* __restrict__ bias,
                                              float* __restrict__ out,
                                              float* __restrict__ sums) {
    __shared__ float lds_s[128];
    __shared__ float lds_s2[128];
    int wave = threadIdx.x >> 6;
    int lane = threadIdx.x & 63;
    int quad = lane >> 4;
    int l15 = lane & 15;
    int rowbase = blockIdx.x * 128 + wave * 32;

    if (STATS) {
        if (threadIdx.x < 128) { lds_s[threadIdx.x] = 0.f; lds_s2[threadIdx.x] = 0.f; }
        __syncthreads();
    }

    floatx4 acc[2][NCT];
#pragma unroll
    for (int w = 0; w < 2; w++)
#pragma unroll
        for (int c = 0; c < NCT; c++) acc[w][c] = (floatx4){0.f, 0.f, 0.f, 0.f};

    int r0 = rowbase + l15;       if (r0 > N_NODES - 1) r0 = N_NODES - 1;
    int r1 = rowbase + 16 + l15;  if (r1 > N_NODES - 1) r1 = N_NODES - 1;

#pragma unroll
    for (int t = 0; t < 8; t++) {
        const unsigned short* base = (t < 4) ? meanb : hb;
        int koff = (t & 3) * 32 + quad * 8;
        short8 a0 = *(const short8*)(base + (size_t)r0 * 128 + koff);
        short8 a1 = *(const short8*)(base + (size_t)r1 * 128 + koff);
#pragma unroll
        for (int c = 0; c < NCT; c++) {
            short8 bf = *(const short8*)(Bp + ((size_t)(t * NCT + c) * 64 + lane) * 8);
            acc[0][c] = __builtin_amdgcn_mfma_f32_16x16x32_bf16(a0, bf, acc[0][c], 0, 0, 0);
            acc[1][c] = __builtin_amdgcn_mfma_f32_16x16x32_bf16(a1, bf, acc[1][c], 0, 0, 0);
        }
    }

#pragma unroll
    for (int c = 0; c < NCT; c++) {
        int col = c * 16 + l15;
        float s = 0.f, s2 = 0.f;
        if (!(NCT * 16 > HSTORE && col >= HSTORE)) {
#pragma unroll
            for (int w = 0; w < 2; w++) {
#pragma unroll
                for (int r = 0; r < 4; r++) {
                    int row = rowbase + w * 16 + quad * 4 + r;
                    if (row < N_NODES) {
                        float v = acc[w][c][r];
                        if (BIAS) v += bias[col];
                        out[(size_t)row * HSTORE + col] = v;
                        if (STATS) { s += v; s2 += v * v; }
                    }
                }
            }
        }
        if (STATS) {
            s += __shfl_xor(s, 16);  s += __shfl_xor(s, 32);
            s2 += __shfl_xor(s2, 16); s2 += __shfl_xor(s2, 32);
            if (quad == 0) {
                atomicAdd(&lds_s[col], s);
                atomicAdd(&lds_s2[col], s2);
            }
        }
    }

    if (STATS) {
        __syncthreads();
        if (threadIdx.x < 128) {
            atomicAdd(&sums[threadIdx.x], lds_s[threadIdx.x]);
            atomicAdd(&sums[128 + threadIdx.x], lds_s2[threadIdx.x]);
        }
    }
}

// ---------------- BN finalize ------------------------------------------------
__global__ void bn_finalize(const float* __restrict__ sums, const float* __restrict__ g,
                            const float* __restrict__ be, float* __restrict__ sc,
                            float* __restrict__ sh) {
    int j = threadIdx.x;
    float inv_n = 1.0f / (float)N_NODES;
    float mu = sums[j] * inv_n;
    float var = sums[128 + j] * inv_n - mu * mu;
    float s = g[j] * rsqrtf(var + EPS);
    sc[j] = s;
    sh[j] = be[j] - mu * s;
}

__global__ void bn_apply(const float* __restrict__ C, const float* __restrict__ sc,
                         const float* __restrict__ sh, unsigned short* __restrict__ ho) {
    int i = blockIdx.x * 256 + threadIdx.x;  // one float4 per thread
    if (i >= N_NODES * 32) return;
    float4 v = ((const float4*)C)[i];
    int c0 = (i * 4) & 127;
    float a = fmaxf(0.f, v.x * sc[c0] + sh[c0]);
    float b = fmaxf(0.f, v.y * sc[c0 + 1] + sh[c0 + 1]);
    float c = fmaxf(0.f, v.z * sc[c0 + 2] + sh[c0 + 2]);
    float d = fmaxf(0.f, v.w * sc[c0 + 3] + sh[c0 + 3]);
    ushort4 o;
    o.x = f2b(a); o.y = f2b(b); o.z = f2b(c); o.w = f2b(d);
    ((ushort4*)ho)[i] = o;
}

// ---------------- host ----------------
extern "C" void kernel_launch(void* const* d_in, const int* in_sizes, int n_in,
                              void* d_out, int out_size, void* d_ws, size_t ws_size,
                              hipStream_t stream) {
    const float* x   = (const float*)d_in[0];
    const int* ei    = (const int*)d_in[1];     // [2, E] int32: row 0 = src, row 1 = dst
    const float* Wl0 = (const float*)d_in[2];
    const float* Wr0 = (const float*)d_in[3];
    const float* Wl1 = (const float*)d_in[4];
    const float* Wr1 = (const float*)d_in[5];
    const float* Wl2 = (const float*)d_in[6];
    const float* Wr2 = (const float*)d_in[7];
    const float* b2  = (const float*)d_in[8];
    const float* g0  = (const float*)d_in[9];
    const float* be0 = (const float*)d_in[10];
    const float* g1  = (const float*)d_in[11];
    const float* be1 = (const float*)d_in[12];

    char* ws = (char*)d_ws;
    size_t off = 0;
    auto alloc = [&](size_t bytes) -> void* {
        void* p = ws + off;
        off += (bytes + 4095) & ~(size_t)4095;
        return p;
    };

    const size_t NB16 = (size_t)N_NODES * 128 * 2;  // 25.6 MB bf16 feature buffer
    unsigned short* xb   = (unsigned short*)alloc(NB16);   // x in bf16; reused as h2
    unsigned short* h1   = (unsigned short*)alloc(NB16);
    unsigned short* mean = (unsigned short*)alloc(NB16);
    float* C             = (float*)alloc((size_t)N_NODES * 128 * 4);
    unsigned int* cnt    = (unsigned int*)alloc((size_t)N_NODES * 4);
    unsigned int* rowptr = (unsigned int*)alloc((size_t)(N_NODES + 1) * 4);
    unsigned int* cursor = (unsigned int*)alloc((size_t)N_NODES * 4);
    int* srclist         = (int*)alloc((size_t)N_EDGES * 4);
    unsigned int* bsum   = (unsigned int*)alloc(512 * 4);
    unsigned int* boff   = (unsigned int*)alloc(512 * 4);
    float* sums          = (float*)alloc(256 * 4);
    float* sc            = (float*)alloc(128 * 4);
    float* sh            = (float*)alloc(128 * 4);
    unsigned short* W0p  = (unsigned short*)alloc(8 * 8 * 64 * 8 * 2);
    unsigned short* W1p  = (unsigned short*)alloc(8 * 8 * 64 * 8 * 2);
    unsigned short* W2p  = (unsigned short*)alloc(3 * 8 * 64 * 8 * 2);
    unsigned short* h2   = xb;  // alias: xb dead after layer-0 GEMM

    const int* srcp = ei;
    const int* dstp = ei + N_EDGES;

    // ---- prep ----
    hipMemsetAsync(cnt, 0, (size_t)N_NODES * 4, stream);
    cvt_f32_bf16<<<12500, 256, 0, stream>>>(x, xb, N_NODES * 32);
    pack_w<<<(8 * 4096 + 255) / 256, 256, 0, stream>>>(Wl0, Wr0, W0p, 128, 8);
    pack_w<<<(8 * 4096 + 255) / 256, 256, 0, stream>>>(Wl1, Wr1, W1p, 128, 8);
    pack_w<<<(3 * 4096 + 255) / 256, 256, 0, stream>>>(Wl2, Wr2, W2p, 40, 3);

    // ---- CSR ----
    hist_k<<<(N_EDGES + 255) / 256, 256, 0, stream>>>(dstp, cnt);
    scan1<<<391, 256, 0, stream>>>(cnt, rowptr, bsum);
    scan2<<<1, 512, 0, stream>>>(bsum, boff, 391);
    scan3<<<391, 256, 0, stream>>>(rowptr, boff, cursor);
    scatter_k<<<(N_EDGES + 255) / 256, 256, 0, stream>>>(srcp, dstp, cursor, srclist);

    // ---- layer 0 ----
    agg_k<<<25000, 256, 0, stream>>>(xb, rowptr, srclist, mean);
    hipMemsetAsync(sums, 0, 256 * 4, stream);
    gemm_k<8, 128, false, true><<<782, 256, 0, stream>>>(mean, xb, W0p, nullptr, C, sums);
    bn_finalize<<<1, 128, 0, stream>>>(sums, g0, be0, sc, sh);
    bn_apply<<<12500, 256, 0, stream>>>(C, sc, sh, h1);

    // ---- layer 1 ----
    agg_k<<<25000, 256, 0, stream>>>(h1, rowptr, srclist, mean);
    hipMemsetAsync(sums, 0, 256 * 4, stream);
    gemm_k<8, 128, false, true><<<782, 256, 0, stream>>>(mean, h1, W1p, nullptr, C, sums);
    bn_finalize<<<1, 128, 0, stream>>>(sums, g1, be1, sc, sh);
    bn_apply<<<12500, 256, 0, stream>>>(C, sc, sh, h2);

    // ---- layer 2 (writes d_out, fp32 [N,40]) ----
    agg_k<<<25000, 256, 0, stream>>>(h2, rowptr, srclist, mean);
    gemm_k<3, 40, true, false><<<782, 256, 0, stream>>>(mean, h2, W2p, b2, (float*)d_out, nullptr);

    (void)in_sizes; (void)n_in; (void)out_size; (void)ws_size;
}

// Round 5
// 470.238 us; speedup vs baseline: 1.7532x; 1.0676x over previous
//
#include <hip/hip_runtime.h>
#include <hip/hip_bf16.h>

#define N_NODES 100000
#define N_EDGES 800000
#define EPS 1e-5f
#define NBANK 32

typedef __attribute__((ext_vector_type(8))) short short8;
typedef __attribute__((ext_vector_type(4))) float floatx4;

__device__ __forceinline__ unsigned short f2b(float f) {
    unsigned int u = __float_as_uint(f);
    u = (u + 0x7fffu + ((u >> 16) & 1u)) >> 16;   // round-to-nearest-even
    return (unsigned short)u;
}
__device__ __forceinline__ float blo(unsigned int u) { return __uint_as_float(u << 16); }
__device__ __forceinline__ float bhi(unsigned int u) { return __uint_as_float(u & 0xffff0000u); }

// ---------------- elementwise convert fp32 -> bf16 (x input) ----------------
__global__ void cvt_f32_bf16(const float* __restrict__ x, unsigned short* __restrict__ o, int n4) {
    int i = blockIdx.x * blockDim.x + threadIdx.x;
    if (i >= n4) return;
    float4 v = ((const float4*)x)[i];
    ushort4 r;
    r.x = f2b(v.x); r.y = f2b(v.y); r.z = f2b(v.z); r.w = f2b(v.w);
    ((ushort4*)o)[i] = r;
}

// ---------------- pack [Wl;Wr] (K=256 x Hreal) into MFMA B-fragment order ----
__global__ void pack_w(const float* __restrict__ Wl, const float* __restrict__ Wr,
                       unsigned short* __restrict__ out, int Hreal, int NCT) {
    int tid = blockIdx.x * blockDim.x + threadIdx.x;
    int total = NCT * 8 * 64 * 8;
    if (tid >= total) return;
    int i = tid & 7;
    int lane = (tid >> 3) & 63;
    int q = tid >> 9;
    int c = q % NCT;
    int t = q / NCT;
    int k = t * 32 + (lane >> 4) * 8 + i;
    int n = c * 16 + (lane & 15);
    float v = 0.f;
    if (n < Hreal) v = (k < 128) ? Wl[k * Hreal + n] : Wr[(k - 128) * Hreal + n];
    out[tid] = f2b(v);
}

// ---------------- CSR build ----------------
__global__ void hist_k(const int* __restrict__ dst, unsigned int* __restrict__ cnt) {
    int e = blockIdx.x * blockDim.x + threadIdx.x;
    if (e < N_EDGES) atomicAdd(&cnt[dst[e]], 1u);
}

__global__ void scan1(const unsigned int* __restrict__ cnt, unsigned int* __restrict__ rowptr,
                      unsigned int* __restrict__ bsum) {
    __shared__ unsigned int sh[256];
    int t = threadIdx.x;
    int i = blockIdx.x * 256 + t;
    unsigned int v = (i < N_NODES) ? cnt[i] : 0u;
    sh[t] = v; __syncthreads();
    for (int off = 1; off < 256; off <<= 1) {
        unsigned int add = (t >= off) ? sh[t - off] : 0u;
        __syncthreads();
        sh[t] += add;
        __syncthreads();
    }
    if (i < N_NODES) rowptr[i] = sh[t] - v;  // exclusive within block
    if (t == 255) bsum[blockIdx.x] = sh[255];
}

__global__ void scan2(const unsigned int* __restrict__ bsum, unsigned int* __restrict__ boff, int nb) {
    __shared__ unsigned int sh[512];
    int t = threadIdx.x;
    unsigned int v = (t < nb) ? bsum[t] : 0u;
    sh[t] = v; __syncthreads();
    for (int off = 1; off < 512; off <<= 1) {
        unsigned int add = (t >= off) ? sh[t - off] : 0u;
        __syncthreads();
        sh[t] += add;
        __syncthreads();
    }
    if (t < nb) boff[t] = sh[t] - v;
}

__global__ void scan3(unsigned int* __restrict__ rowptr, const unsigned int* __restrict__ boff,
                      unsigned int* __restrict__ cursor) {
    int i = blockIdx.x * 256 + threadIdx.x;
    if (i < N_NODES) {
        unsigned int r = rowptr[i] + boff[blockIdx.x];
        rowptr[i] = r;
        cursor[i] = r;
    }
    if (i == N_NODES) rowptr[N_NODES] = N_EDGES;
}

// XCD-partitioned scatter (R4: random 4B srclist writes caused 55 MB HBM write
// = full-line flush per edge, cross-XCD dirty-line churn). group = blk&7 maps
// round-robin to XCDs; each group scans ALL edges (L3-resident, 8x read) but
// writes only its 1/8 node-range slice of srclist (~400 KB) -> dirty lines stay
// in one XCD's L2 and merge before writeback.
#define SC_GRPBLK 40
__global__ void __launch_bounds__(256) scatter_k(const int* __restrict__ src,
                                                 const int* __restrict__ dst,
                                                 unsigned int* __restrict__ cursor,
                                                 int* __restrict__ srclist) {
    int group = blockIdx.x & 7;
    int gblk = blockIdx.x >> 3;
    int lo = group * (N_NODES / 8), hi = lo + (N_NODES / 8);   // 12500-node slices
    if (group == 7) hi = N_NODES;
    const int per = (N_EDGES + SC_GRPBLK - 1) / SC_GRPBLK;
    int start = gblk * per;
    int end = start + per; if (end > N_EDGES) end = N_EDGES;
    for (int e = start + threadIdx.x; e < end; e += 256) {
        int d = dst[e];
        if (d >= lo && d < hi) {
            unsigned int p = atomicAdd(&cursor[d], 1u);
            srclist[p] = src[e];
        }
    }
}

// ---------------- mean aggregation ------------------------------------------
// One wave per node; lanes = 4 groups x 16. Group g gathers a full neighbor
// row with dwordx4 (1 KiB / instruction, 4 edges in parallel), unrolled x2
// (8 rows in flight). Cross-group butterfly reduce at the end.
__global__ void __launch_bounds__(256) agg_k(const unsigned short* __restrict__ h,
                                             const unsigned int* __restrict__ rowptr,
                                             const int* __restrict__ srclist,
                                             unsigned short* __restrict__ mean) {
    int tid = blockIdx.x * 256 + threadIdx.x;
    int node = tid >> 6;
    int lane = tid & 63;
    if (node >= N_NODES) return;
    int g = lane >> 4, l = lane & 15;
    unsigned int b = rowptr[node], e = rowptr[node + 1];
    const uint4* hp = (const uint4*)h;
    float a0 = 0.f, a1 = 0.f, a2 = 0.f, a3 = 0.f, a4 = 0.f, a5 = 0.f, a6 = 0.f, a7 = 0.f;
    float b0 = 0.f, b1 = 0.f, b2 = 0.f, b3 = 0.f, b4 = 0.f, b5 = 0.f, b6 = 0.f, b7 = 0.f;
    unsigned int p = b;
    for (; p + 8 <= e; p += 8) {
        int s0 = srclist[p + g];
        int s1 = srclist[p + 4 + g];
        uint4 u0 = hp[(size_t)s0 * 16 + l];
        uint4 u1 = hp[(size_t)s1 * 16 + l];
        a0 += blo(u0.x); a1 += bhi(u0.x); a2 += blo(u0.y); a3 += bhi(u0.y);
        a4 += blo(u0.z); a5 += bhi(u0.z); a6 += blo(u0.w); a7 += bhi(u0.w);
        b0 += blo(u1.x); b1 += bhi(u1.x); b2 += blo(u1.y); b3 += bhi(u1.y);
        b4 += blo(u1.z); b5 += bhi(u1.z); b6 += blo(u1.w); b7 += bhi(u1.w);
    }
    if (p + 4 <= e) {
        int s0 = srclist[p + g];
        uint4 u0 = hp[(size_t)s0 * 16 + l];
        a0 += blo(u0.x); a1 += bhi(u0.x); a2 += blo(u0.y); a3 += bhi(u0.y);
        a4 += blo(u0.z); a5 += bhi(u0.z); a6 += blo(u0.w); a7 += bhi(u0.w);
        p += 4;
    }
    unsigned int rem = e - p;  // 0..3
    if ((unsigned int)g < rem) {
        int s1 = srclist[p + g];
        uint4 u1 = hp[(size_t)s1 * 16 + l];
        b0 += blo(u1.x); b1 += bhi(u1.x); b2 += blo(u1.y); b3 += bhi(u1.y);
        b4 += blo(u1.z); b5 += bhi(u1.z); b6 += blo(u1.w); b7 += bhi(u1.w);
    }
    unsigned int deg = e - b;
    float r = 1.0f / (float)(deg > 1u ? deg : 1u);
    float f0 = a0 + b0, f1 = a1 + b1, f2 = a2 + b2, f3 = a3 + b3;
    float f4 = a4 + b4, f5 = a5 + b5, f6 = a6 + b6, f7 = a7 + b7;
    f0 += __shfl_xor(f0, 16); f0 += __shfl_xor(f0, 32);
    f1 += __shfl_xor(f1, 16); f1 += __shfl_xor(f1, 32);
    f2 += __shfl_xor(f2, 16); f2 += __shfl_xor(f2, 32);
    f3 += __shfl_xor(f3, 16); f3 += __shfl_xor(f3, 32);
    f4 += __shfl_xor(f4, 16); f4 += __shfl_xor(f4, 32);
    f5 += __shfl_xor(f5, 16); f5 += __shfl_xor(f5, 32);
    f6 += __shfl_xor(f6, 16); f6 += __shfl_xor(f6, 32);
    f7 += __shfl_xor(f7, 16); f7 += __shfl_xor(f7, 32);
    if (g == 0) {
        uint4 o;
        o.x = (unsigned int)f2b(f0 * r) | ((unsigned int)f2b(f1 * r) << 16);
        o.y = (unsigned int)f2b(f2 * r) | ((unsigned int)f2b(f3 * r) << 16);
        o.z = (unsigned int)f2b(f4 * r) | ((unsigned int)f2b(f5 * r) << 16);
        o.w = (unsigned int)f2b(f6 * r) | ((unsigned int)f2b(f7 * r) << 16);
        ((uint4*)mean)[(size_t)node * 16 + l] = o;
    }
}

// ---------------- GEMM: C[N x HSTORE] = [mean|h] @ packedB, bf16 MFMA --------
// STATS: fused BN stats; 32-bank replicated global accumulators (R4: 200K
// atomics on 16 lines serialized cross-XCD). OBF16: write C as bf16 (pre-BN
// rounding ~0.4% rel, renormalized by BN) to halve write + bn_apply read.
template <int NCT, int HSTORE, bool BIAS, bool STATS, bool OBF16>
__global__ void __launch_bounds__(256) gemm_k(const unsigned short* __restrict__ meanb,
                                              const unsigned short* __restrict__ hb,
                                              const unsigned short* __restrict__ Bp,
                                              const float* __restrict__ bias,
                                              void* __restrict__ outv,
                                              float* __restrict__ sums) {
    __shared__ float lds_s[128];
    __shared__ float lds_s2[128];
    int wave = threadIdx.x >> 6;
    int lane = threadIdx.x & 63;
    int quad = lane >> 4;
    int l15 = lane & 15;
    int rowbase = blockIdx.x * 128 + wave * 32;

    if (STATS) {
        if (threadIdx.x < 128) { lds_s[threadIdx.x] = 0.f; lds_s2[threadIdx.x] = 0.f; }
        __syncthreads();
    }

    floatx4 acc[2][NCT];
#pragma unroll
    for (int w = 0; w < 2; w++)
#pragma unroll
        for (int c = 0; c < NCT; c++) acc[w][c] = (floatx4){0.f, 0.f, 0.f, 0.f};

    int r0 = rowbase + l15;       if (r0 > N_NODES - 1) r0 = N_NODES - 1;
    int r1 = rowbase + 16 + l15;  if (r1 > N_NODES - 1) r1 = N_NODES - 1;

#pragma unroll
    for (int t = 0; t < 8; t++) {
        const unsigned short* base = (t < 4) ? meanb : hb;
        int koff = (t & 3) * 32 + quad * 8;
        short8 a0 = *(const short8*)(base + (size_t)r0 * 128 + koff);
        short8 a1 = *(const short8*)(base + (size_t)r1 * 128 + koff);
#pragma unroll
        for (int c = 0; c < NCT; c++) {
            short8 bf = *(const short8*)(Bp + ((size_t)(t * NCT + c) * 64 + lane) * 8);
            acc[0][c] = __builtin_amdgcn_mfma_f32_16x16x32_bf16(a0, bf, acc[0][c], 0, 0, 0);
            acc[1][c] = __builtin_amdgcn_mfma_f32_16x16x32_bf16(a1, bf, acc[1][c], 0, 0, 0);
        }
    }

    float* outf = (float*)outv;
    unsigned short* outb = (unsigned short*)outv;
#pragma unroll
    for (int c = 0; c < NCT; c++) {
        int col = c * 16 + l15;
        float s = 0.f, s2 = 0.f;
        if (!(NCT * 16 > HSTORE && col >= HSTORE)) {
#pragma unroll
            for (int w = 0; w < 2; w++) {
#pragma unroll
                for (int r = 0; r < 4; r++) {
                    int row = rowbase + w * 16 + quad * 4 + r;
                    if (row < N_NODES) {
                        float v = acc[w][c][r];
                        if (BIAS) v += bias[col];
                        if (OBF16) outb[(size_t)row * HSTORE + col] = f2b(v);
                        else       outf[(size_t)row * HSTORE + col] = v;
                        if (STATS) { s += v; s2 += v * v; }
                    }
                }
            }
        }
        if (STATS) {
            s += __shfl_xor(s, 16);  s += __shfl_xor(s, 32);
            s2 += __shfl_xor(s2, 16); s2 += __shfl_xor(s2, 32);
            if (quad == 0) {
                atomicAdd(&lds_s[col], s);
                atomicAdd(&lds_s2[col], s2);
            }
        }
    }

    if (STATS) {
        __syncthreads();
        if (threadIdx.x < 128) {
            int bank = blockIdx.x & (NBANK - 1);
            atomicAdd(&sums[bank * 256 + threadIdx.x], lds_s[threadIdx.x]);
            atomicAdd(&sums[bank * 256 + 128 + threadIdx.x], lds_s2[threadIdx.x]);
        }
    }
}

// ---------------- BN finalize (reduce 32 banks) ------------------------------
__global__ void bn_finalize(const float* __restrict__ sums, const float* __restrict__ g,
                            const float* __restrict__ be, float* __restrict__ sc,
                            float* __restrict__ sh) {
    __shared__ float lds[256];
    int t = threadIdx.x;
    float s = 0.f;
#pragma unroll 8
    for (int bk = 0; bk < NBANK; bk++) s += sums[bk * 256 + t];
    lds[t] = s;
    __syncthreads();
    if (t < 128) {
        float inv_n = 1.0f / (float)N_NODES;
        float mu = lds[t] * inv_n;
        float var = lds[128 + t] * inv_n - mu * mu;
        float sf = g[t] * rsqrtf(var + EPS);
        sc[t] = sf;
        sh[t] = be[t] - mu * sf;
    }
}

// ---------------- BN apply: bf16 in -> bf16 out, 8 elems/thread --------------
__global__ void bn_apply(const unsigned int* __restrict__ Cb, const float* __restrict__ sc,
                         const float* __restrict__ sh, unsigned short* __restrict__ ho) {
    int i = blockIdx.x * 256 + threadIdx.x;  // one uint4 = 8 bf16
    if (i >= N_NODES * 16) return;
    uint4 v = ((const uint4*)Cb)[i];
    int c0 = (i * 8) & 127;
    uint4 o;
    float e0 = fmaxf(0.f, blo(v.x) * sc[c0 + 0] + sh[c0 + 0]);
    float e1 = fmaxf(0.f, bhi(v.x) * sc[c0 + 1] + sh[c0 + 1]);
    float e2 = fmaxf(0.f, blo(v.y) * sc[c0 + 2] + sh[c0 + 2]);
    float e3 = fmaxf(0.f, bhi(v.y) * sc[c0 + 3] + sh[c0 + 3]);
    float e4 = fmaxf(0.f, blo(v.z) * sc[c0 + 4] + sh[c0 + 4]);
    float e5 = fmaxf(0.f, bhi(v.z) * sc[c0 + 5] + sh[c0 + 5]);
    float e6 = fmaxf(0.f, blo(v.w) * sc[c0 + 6] + sh[c0 + 6]);
    float e7 = fmaxf(0.f, bhi(v.w) * sc[c0 + 7] + sh[c0 + 7]);
    o.x = (unsigned int)f2b(e0) | ((unsigned int)f2b(e1) << 16);
    o.y = (unsigned int)f2b(e2) | ((unsigned int)f2b(e3) << 16);
    o.z = (unsigned int)f2b(e4) | ((unsigned int)f2b(e5) << 16);
    o.w = (unsigned int)f2b(e6) | ((unsigned int)f2b(e7) << 16);
    ((uint4*)ho)[i] = o;
}

// ---------------- host ----------------
extern "C" void kernel_launch(void* const* d_in, const int* in_sizes, int n_in,
                              void* d_out, int out_size, void* d_ws, size_t ws_size,
                              hipStream_t stream) {
    const float* x   = (const float*)d_in[0];
    const int* ei    = (const int*)d_in[1];     // [2, E] int32: row 0 = src, row 1 = dst
    const float* Wl0 = (const float*)d_in[2];
    const float* Wr0 = (const float*)d_in[3];
    const float* Wl1 = (const float*)d_in[4];
    const float* Wr1 = (const float*)d_in[5];
    const float* Wl2 = (const float*)d_in[6];
    const float* Wr2 = (const float*)d_in[7];
    const float* b2  = (const float*)d_in[8];
    const float* g0  = (const float*)d_in[9];
    const float* be0 = (const float*)d_in[10];
    const float* g1  = (const float*)d_in[11];
    const float* be1 = (const float*)d_in[12];

    char* ws = (char*)d_ws;
    size_t off = 0;
    auto alloc = [&](size_t bytes) -> void* {
        void* p = ws + off;
        off += (bytes + 4095) & ~(size_t)4095;
        return p;
    };

    const size_t NB16 = (size_t)N_NODES * 128 * 2;  // 25.6 MB bf16 feature buffer
    unsigned short* xb   = (unsigned short*)alloc(NB16);   // x in bf16; reused as h2
    unsigned short* h1   = (unsigned short*)alloc(NB16);
    unsigned short* mean = (unsigned short*)alloc(NB16);
    unsigned short* C    = (unsigned short*)alloc(NB16);   // pre-BN bf16
    unsigned int* cnt    = (unsigned int*)alloc((size_t)N_NODES * 4);
    unsigned int* rowptr = (unsigned int*)alloc((size_t)(N_NODES + 1) * 4);
    unsigned int* cursor = (unsigned int*)alloc((size_t)N_NODES * 4);
    int* srclist         = (int*)alloc((size_t)N_EDGES * 4);
    unsigned int* bsum   = (unsigned int*)alloc(512 * 4);
    unsigned int* boff   = (unsigned int*)alloc(512 * 4);
    float* sums          = (float*)alloc(NBANK * 256 * 4);
    float* sc            = (float*)alloc(128 * 4);
    float* sh            = (float*)alloc(128 * 4);
    unsigned short* W0p  = (unsigned short*)alloc(8 * 8 * 64 * 8 * 2);
    unsigned short* W1p  = (unsigned short*)alloc(8 * 8 * 64 * 8 * 2);
    unsigned short* W2p  = (unsigned short*)alloc(3 * 8 * 64 * 8 * 2);
    unsigned short* h2   = xb;  // alias: xb dead after layer-0 GEMM

    const int* srcp = ei;
    const int* dstp = ei + N_EDGES;

    // ---- prep ----
    hipMemsetAsync(cnt, 0, (size_t)N_NODES * 4, stream);
    cvt_f32_bf16<<<12500, 256, 0, stream>>>(x, xb, N_NODES * 32);
    pack_w<<<(8 * 4096 + 255) / 256, 256, 0, stream>>>(Wl0, Wr0, W0p, 128, 8);
    pack_w<<<(8 * 4096 + 255) / 256, 256, 0, stream>>>(Wl1, Wr1, W1p, 128, 8);
    pack_w<<<(3 * 4096 + 255) / 256, 256, 0, stream>>>(Wl2, Wr2, W2p, 40, 3);

    // ---- CSR ----
    hist_k<<<(N_EDGES + 255) / 256, 256, 0, stream>>>(dstp, cnt);
    scan1<<<391, 256, 0, stream>>>(cnt, rowptr, bsum);
    scan2<<<1, 512, 0, stream>>>(bsum, boff, 391);
    scan3<<<391, 256, 0, stream>>>(rowptr, boff, cursor);
    scatter_k<<<8 * SC_GRPBLK, 256, 0, stream>>>(srcp, dstp, cursor, srclist);

    // ---- layer 0 ----
    agg_k<<<25000, 256, 0, stream>>>(xb, rowptr, srclist, mean);
    hipMemsetAsync(sums, 0, NBANK * 256 * 4, stream);
    gemm_k<8, 128, false, true, true><<<782, 256, 0, stream>>>(mean, xb, W0p, nullptr, C, sums);
    bn_finalize<<<1, 256, 0, stream>>>(sums, g0, be0, sc, sh);
    bn_apply<<<6250, 256, 0, stream>>>((const unsigned int*)C, sc, sh, h1);

    // ---- layer 1 ----
    agg_k<<<25000, 256, 0, stream>>>(h1, rowptr, srclist, mean);
    hipMemsetAsync(sums, 0, NBANK * 256 * 4, stream);
    gemm_k<8, 128, false, true, true><<<782, 256, 0, stream>>>(mean, h1, W1p, nullptr, C, sums);
    bn_finalize<<<1, 256, 0, stream>>>(sums, g1, be1, sc, sh);
    bn_apply<<<6250, 256, 0, stream>>>((const unsigned int*)C, sc, sh, h2);

    // ---- layer 2 (writes d_out, fp32 [N,40]) ----
    agg_k<<<25000, 256, 0, stream>>>(h2, rowptr, srclist, mean);
    gemm_k<3, 40, true, false, false><<<782, 256, 0, stream>>>(mean, h2, W2p, b2, d_out, nullptr);

    (void)in_sizes; (void)n_in; (void)out_size; (void)ws_size;
}

// Round 6
// 453.172 us; speedup vs baseline: 1.8192x; 1.0377x over previous
//
#include <hip/hip_runtime.h>
#include <hip/hip_bf16.h>

#define N_NODES 100000
#define N_EDGES 800000
#define EPS 1e-5f
#define NBANK 32
#define HB_BLOCKS 256
#define HB_PER 3125          // 256 * 3125 = 800000 exactly
#define CS_GPB 64            // cscatter blocks per coarse bucket
#define BUCKET_N 12500       // 8 * 12500 = 100000 exactly

typedef __attribute__((ext_vector_type(8))) short short8;
typedef __attribute__((ext_vector_type(4))) float floatx4;

__device__ __forceinline__ unsigned short f2b(float f) {
    unsigned int u = __float_as_uint(f);
    u = (u + 0x7fffu + ((u >> 16) & 1u)) >> 16;   // round-to-nearest-even
    return (unsigned short)u;
}
__device__ __forceinline__ float blo(unsigned int u) { return __uint_as_float(u << 16); }
__device__ __forceinline__ float bhi(unsigned int u) { return __uint_as_float(u & 0xffff0000u); }

// ---------------- elementwise convert fp32 -> bf16 (x input) ----------------
__global__ void cvt_f32_bf16(const float* __restrict__ x, unsigned short* __restrict__ o, int n4) {
    int i = blockIdx.x * blockDim.x + threadIdx.x;
    if (i >= n4) return;
    float4 v = ((const float4*)x)[i];
    ushort4 r;
    r.x = f2b(v.x); r.y = f2b(v.y); r.z = f2b(v.z); r.w = f2b(v.w);
    ((ushort4*)o)[i] = r;
}

// ---------------- pack [Wl;Wr] (K=256 x Hreal) into MFMA B-fragment order ----
__global__ void pack_w(const float* __restrict__ Wl, const float* __restrict__ Wr,
                       unsigned short* __restrict__ out, int Hreal, int NCT) {
    int tid = blockIdx.x * blockDim.x + threadIdx.x;
    int total = NCT * 8 * 64 * 8;
    if (tid >= total) return;
    int i = tid & 7;
    int lane = (tid >> 3) & 63;
    int q = tid >> 9;
    int c = q % NCT;
    int t = q / NCT;
    int k = t * 32 + (lane >> 4) * 8 + i;
    int n = c * 16 + (lane & 15);
    float v = 0.f;
    if (n < Hreal) v = (k < 128) ? Wl[k * Hreal + n] : Wr[(k - 128) * Hreal + n];
    out[tid] = f2b(v);
}

// ---------------- CSR build: two-level counting sort -------------------------
// (R5 post-mortem: single random scatter = 29-55 MB HBM write from cross-XCD
//  dirty-line churn on a 3.2 MB array. Now: coarse 8-bucket deterministic
//  scatter with per-block private output ranges, then fine scatter random only
//  within a 400 KB XCD-local region.)

// per-node counts (global atomics) + per-block coarse 8-bucket hist (LDS)
__global__ void __launch_bounds__(256) hist_k(const int* __restrict__ dst,
                                              unsigned int* __restrict__ cnt,
                                              unsigned int* __restrict__ bhist) {
    __shared__ unsigned int lh[8];
    if (threadIdx.x < 8) lh[threadIdx.x] = 0;
    __syncthreads();
    int start = blockIdx.x * HB_PER;
    for (int i = threadIdx.x; i < HB_PER; i += 256) {
        int d = dst[start + i];
        atomicAdd(&cnt[d], 1u);
        atomicAdd(&lh[(unsigned int)d / BUCKET_N], 1u);
    }
    __syncthreads();
    if (threadIdx.x < 8) bhist[threadIdx.x * HB_BLOCKS + blockIdx.x] = lh[threadIdx.x];
}

// exclusive scan of bhist[8*256] in place (bucket-major flat order)
__global__ void bscan(unsigned int* __restrict__ A) {
    __shared__ unsigned int part[256];
    int t = threadIdx.x;
    unsigned int v[8];
    unsigned int s = 0;
#pragma unroll
    for (int i = 0; i < 8; i++) { v[i] = A[t * 8 + i]; s += v[i]; }
    part[t] = s; __syncthreads();
    for (int off = 1; off < 256; off <<= 1) {
        unsigned int add = (t >= off) ? part[t - off] : 0u;
        __syncthreads();
        part[t] += add;
        __syncthreads();
    }
    unsigned int base = part[t] - s;  // exclusive
#pragma unroll
    for (int i = 0; i < 8; i++) { unsigned int old = v[i]; A[t * 8 + i] = base; base += old; }
}

// coarse scatter: block writes each bucket's edges to its private contiguous
// sub-range (no global atomics). pack = src | (dst_local << 17).
__global__ void __launch_bounds__(256) bscatter(const int* __restrict__ src,
                                                const int* __restrict__ dst,
                                                const unsigned int* __restrict__ boffs,
                                                unsigned int* __restrict__ ebuf) {
    __shared__ unsigned int cur[8];
    if (threadIdx.x < 8) cur[threadIdx.x] = boffs[threadIdx.x * HB_BLOCKS + blockIdx.x];
    __syncthreads();
    int start = blockIdx.x * HB_PER;
    for (int i = threadIdx.x; i < HB_PER; i += 256) {
        int d = dst[start + i];
        int s = src[start + i];
        unsigned int b = (unsigned int)d / BUCKET_N;
        unsigned int dl = (unsigned int)d - b * BUCKET_N;
        unsigned int pos = atomicAdd(&cur[b], 1u);
        ebuf[pos] = (unsigned int)s | (dl << 17);
    }
}

// fine scatter: group g = blk&7 (XCD round-robin) handles coarse bucket g.
// Reads coalesced; writes random only within the group's ~400 KB slice.
__global__ void __launch_bounds__(256) cscatter(const unsigned int* __restrict__ ebuf,
                                                const unsigned int* __restrict__ rowptr,
                                                unsigned int* __restrict__ cursor,
                                                int* __restrict__ srclist) {
    int g = blockIdx.x & 7;
    int gblk = blockIdx.x >> 3;
    unsigned int estart = rowptr[g * BUCKET_N];
    unsigned int eend = (g == 7) ? N_EDGES : rowptr[(g + 1) * BUCKET_N];
    unsigned int nume = eend - estart;
    unsigned int per = (nume + CS_GPB - 1) / CS_GPB;
    unsigned int s0 = estart + gblk * per;
    unsigned int s1 = s0 + per; if (s1 > eend) s1 = eend;
    unsigned int nodebase = g * BUCKET_N;
    for (unsigned int i = s0 + threadIdx.x; i < s1; i += 256) {
        unsigned int p = ebuf[i];
        unsigned int s = p & 0x1FFFFu;
        unsigned int node = nodebase + (p >> 17);
        unsigned int pos = atomicAdd(&cursor[node], 1u);
        srclist[pos] = (int)s;
    }
}

__global__ void scan1(const unsigned int* __restrict__ cnt, unsigned int* __restrict__ rowptr,
                      unsigned int* __restrict__ bsum) {
    __shared__ unsigned int sh[256];
    int t = threadIdx.x;
    int i = blockIdx.x * 256 + t;
    unsigned int v = (i < N_NODES) ? cnt[i] : 0u;
    sh[t] = v; __syncthreads();
    for (int off = 1; off < 256; off <<= 1) {
        unsigned int add = (t >= off) ? sh[t - off] : 0u;
        __syncthreads();
        sh[t] += add;
        __syncthreads();
    }
    if (i < N_NODES) rowptr[i] = sh[t] - v;  // exclusive within block
    if (t == 255) bsum[blockIdx.x] = sh[255];
}

__global__ void scan2(const unsigned int* __restrict__ bsum, unsigned int* __restrict__ boff, int nb) {
    __shared__ unsigned int sh[512];
    int t = threadIdx.x;
    unsigned int v = (t < nb) ? bsum[t] : 0u;
    sh[t] = v; __syncthreads();
    for (int off = 1; off < 512; off <<= 1) {
        unsigned int add = (t >= off) ? sh[t - off] : 0u;
        __syncthreads();
        sh[t] += add;
        __syncthreads();
    }
    if (t < nb) boff[t] = sh[t] - v;
}

__global__ void scan3(unsigned int* __restrict__ rowptr, const unsigned int* __restrict__ boff,
                      unsigned int* __restrict__ cursor) {
    int i = blockIdx.x * 256 + threadIdx.x;
    if (i < N_NODES) {
        unsigned int r = rowptr[i] + boff[blockIdx.x];
        rowptr[i] = r;
        cursor[i] = r;
    }
    if (i == N_NODES) rowptr[N_NODES] = N_EDGES;
}

// ---------------- mean aggregation ------------------------------------------
// One wave per node; lanes = 4 groups x 16. Group g gathers a full neighbor
// row with dwordx4 (1 KiB / instruction, 4 edges in parallel), unrolled x2
// (8 rows in flight). Cross-group butterfly reduce at the end.
__global__ void __launch_bounds__(256) agg_k(const unsigned short* __restrict__ h,
                                             const unsigned int* __restrict__ rowptr,
                                             const int* __restrict__ srclist,
                                             unsigned short* __restrict__ mean) {
    int tid = blockIdx.x * 256 + threadIdx.x;
    int node = tid >> 6;
    int lane = tid & 63;
    if (node >= N_NODES) return;
    int g = lane >> 4, l = lane & 15;
    unsigned int b = rowptr[node], e = rowptr[node + 1];
    const uint4* hp = (const uint4*)h;
    float a0 = 0.f, a1 = 0.f, a2 = 0.f, a3 = 0.f, a4 = 0.f, a5 = 0.f, a6 = 0.f, a7 = 0.f;
    float b0 = 0.f, b1 = 0.f, b2 = 0.f, b3 = 0.f, b4 = 0.f, b5 = 0.f, b6 = 0.f, b7 = 0.f;
    unsigned int p = b;
    for (; p + 8 <= e; p += 8) {
        int s0 = srclist[p + g];
        int s1 = srclist[p + 4 + g];
        uint4 u0 = hp[(size_t)s0 * 16 + l];
        uint4 u1 = hp[(size_t)s1 * 16 + l];
        a0 += blo(u0.x); a1 += bhi(u0.x); a2 += blo(u0.y); a3 += bhi(u0.y);
        a4 += blo(u0.z); a5 += bhi(u0.z); a6 += blo(u0.w); a7 += bhi(u0.w);
        b0 += blo(u1.x); b1 += bhi(u1.x); b2 += blo(u1.y); b3 += bhi(u1.y);
        b4 += blo(u1.z); b5 += bhi(u1.z); b6 += blo(u1.w); b7 += bhi(u1.w);
    }
    if (p + 4 <= e) {
        int s0 = srclist[p + g];
        uint4 u0 = hp[(size_t)s0 * 16 + l];
        a0 += blo(u0.x); a1 += bhi(u0.x); a2 += blo(u0.y); a3 += bhi(u0.y);
        a4 += blo(u0.z); a5 += bhi(u0.z); a6 += blo(u0.w); a7 += bhi(u0.w);
        p += 4;
    }
    unsigned int rem = e - p;  // 0..3
    if ((unsigned int)g < rem) {
        int s1 = srclist[p + g];
        uint4 u1 = hp[(size_t)s1 * 16 + l];
        b0 += blo(u1.x); b1 += bhi(u1.x); b2 += blo(u1.y); b3 += bhi(u1.y);
        b4 += blo(u1.z); b5 += bhi(u1.z); b6 += blo(u1.w); b7 += bhi(u1.w);
    }
    unsigned int deg = e - b;
    float r = 1.0f / (float)(deg > 1u ? deg : 1u);
    float f0 = a0 + b0, f1 = a1 + b1, f2 = a2 + b2, f3 = a3 + b3;
    float f4 = a4 + b4, f5 = a5 + b5, f6 = a6 + b6, f7 = a7 + b7;
    f0 += __shfl_xor(f0, 16); f0 += __shfl_xor(f0, 32);
    f1 += __shfl_xor(f1, 16); f1 += __shfl_xor(f1, 32);
    f2 += __shfl_xor(f2, 16); f2 += __shfl_xor(f2, 32);
    f3 += __shfl_xor(f3, 16); f3 += __shfl_xor(f3, 32);
    f4 += __shfl_xor(f4, 16); f4 += __shfl_xor(f4, 32);
    f5 += __shfl_xor(f5, 16); f5 += __shfl_xor(f5, 32);
    f6 += __shfl_xor(f6, 16); f6 += __shfl_xor(f6, 32);
    f7 += __shfl_xor(f7, 16); f7 += __shfl_xor(f7, 32);
    if (g == 0) {
        uint4 o;
        o.x = (unsigned int)f2b(f0 * r) | ((unsigned int)f2b(f1 * r) << 16);
        o.y = (unsigned int)f2b(f2 * r) | ((unsigned int)f2b(f3 * r) << 16);
        o.z = (unsigned int)f2b(f4 * r) | ((unsigned int)f2b(f5 * r) << 16);
        o.w = (unsigned int)f2b(f6 * r) | ((unsigned int)f2b(f7 * r) << 16);
        ((uint4*)mean)[(size_t)node * 16 + l] = o;
    }
}

// ---------------- GEMM: C[N x HSTORE] = [mean|h] @ packedB, bf16 MFMA --------
// STATS: fused BN stats; 32-bank replicated global accumulators. OBF16: write
// C as bf16 (renormalized by BN) to halve write + bn_apply read.
template <int NCT, int HSTORE, bool BIAS, bool STATS, bool OBF16>
__global__ void __launch_bounds__(256) gemm_k(const unsigned short* __restrict__ meanb,
                                              const unsigned short* __restrict__ hb,
                                              const unsigned short* __restrict__ Bp,
                                              const float* __restrict__ bias,
                                              void* __restrict__ outv,
                                              float* __restrict__ sums) {
    __shared__ float lds_s[128];
    __shared__ float lds_s2[128];
    int wave = threadIdx.x >> 6;
    int lane = threadIdx.x & 63;
    int quad = lane >> 4;
    int l15 = lane & 15;
    int rowbase = blockIdx.x * 128 + wave * 32;

    if (STATS) {
        if (threadIdx.x < 128) { lds_s[threadIdx.x] = 0.f; lds_s2[threadIdx.x] = 0.f; }
        __syncthreads();
    }

    floatx4 acc[2][NCT];
#pragma unroll
    for (int w = 0; w < 2; w++)
#pragma unroll
        for (int c = 0; c < NCT; c++) acc[w][c] = (floatx4){0.f, 0.f, 0.f, 0.f};

    int r0 = rowbase + l15;       if (r0 > N_NODES - 1) r0 = N_NODES - 1;
    int r1 = rowbase + 16 + l15;  if (r1 > N_NODES - 1) r1 = N_NODES - 1;

#pragma unroll
    for (int t = 0; t < 8; t++) {
        const unsigned short* base = (t < 4) ? meanb : hb;
        int koff = (t & 3) * 32 + quad * 8;
        short8 a0 = *(const short8*)(base + (size_t)r0 * 128 + koff);
        short8 a1 = *(const short8*)(base + (size_t)r1 * 128 + koff);
#pragma unroll
        for (int c = 0; c < NCT; c++) {
            short8 bf = *(const short8*)(Bp + ((size_t)(t * NCT + c) * 64 + lane) * 8);
            acc[0][c] = __builtin_amdgcn_mfma_f32_16x16x32_bf16(a0, bf, acc[0][c], 0, 0, 0);
            acc[1][c] = __builtin_amdgcn_mfma_f32_16x16x32_bf16(a1, bf, acc[1][c], 0, 0, 0);
        }
    }

    float* outf = (float*)outv;
    unsigned short* outb = (unsigned short*)outv;
#pragma unroll
    for (int c = 0; c < NCT; c++) {
        int col = c * 16 + l15;
        float s = 0.f, s2 = 0.f;
        if (!(NCT * 16 > HSTORE && col >= HSTORE)) {
#pragma unroll
            for (int w = 0; w < 2; w++) {
#pragma unroll
                for (int r = 0; r < 4; r++) {
                    int row = rowbase + w * 16 + quad * 4 + r;
                    if (row < N_NODES) {
                        float v = acc[w][c][r];
                        if (BIAS) v += bias[col];
                        if (OBF16) outb[(size_t)row * HSTORE + col] = f2b(v);
                        else       outf[(size_t)row * HSTORE + col] = v;
                        if (STATS) { s += v; s2 += v * v; }
                    }
                }
            }
        }
        if (STATS) {
            s += __shfl_xor(s, 16);  s += __shfl_xor(s, 32);
            s2 += __shfl_xor(s2, 16); s2 += __shfl_xor(s2, 32);
            if (quad == 0) {
                atomicAdd(&lds_s[col], s);
                atomicAdd(&lds_s2[col], s2);
            }
        }
    }

    if (STATS) {
        __syncthreads();
        if (threadIdx.x < 128) {
            int bank = blockIdx.x & (NBANK - 1);
            atomicAdd(&sums[bank * 256 + threadIdx.x], lds_s[threadIdx.x]);
            atomicAdd(&sums[bank * 256 + 128 + threadIdx.x], lds_s2[threadIdx.x]);
        }
    }
}

// ---------------- BN finalize (reduce 32 banks) ------------------------------
__global__ void bn_finalize(const float* __restrict__ sums, const float* __restrict__ g,
                            const float* __restrict__ be, float* __restrict__ sc,
                            float* __restrict__ sh) {
    __shared__ float lds[256];
    int t = threadIdx.x;
    float s = 0.f;
#pragma unroll 8
    for (int bk = 0; bk < NBANK; bk++) s += sums[bk * 256 + t];
    lds[t] = s;
    __syncthreads();
    if (t < 128) {
        float inv_n = 1.0f / (float)N_NODES;
        float mu = lds[t] * inv_n;
        float var = lds[128 + t] * inv_n - mu * mu;
        float sf = g[t] * rsqrtf(var + EPS);
        sc[t] = sf;
        sh[t] = be[t] - mu * sf;
    }
}

// ---------------- BN apply: bf16 in -> bf16 out, 8 elems/thread --------------
__global__ void bn_apply(const unsigned int* __restrict__ Cb, const float* __restrict__ sc,
                         const float* __restrict__ sh, unsigned short* __restrict__ ho) {
    int i = blockIdx.x * 256 + threadIdx.x;  // one uint4 = 8 bf16
    if (i >= N_NODES * 16) return;
    uint4 v = ((const uint4*)Cb)[i];
    int c0 = (i * 8) & 127;
    uint4 o;
    float e0 = fmaxf(0.f, blo(v.x) * sc[c0 + 0] + sh[c0 + 0]);
    float e1 = fmaxf(0.f, bhi(v.x) * sc[c0 + 1] + sh[c0 + 1]);
    float e2 = fmaxf(0.f, blo(v.y) * sc[c0 + 2] + sh[c0 + 2]);
    float e3 = fmaxf(0.f, bhi(v.y) * sc[c0 + 3] + sh[c0 + 3]);
    float e4 = fmaxf(0.f, blo(v.z) * sc[c0 + 4] + sh[c0 + 4]);
    float e5 = fmaxf(0.f, bhi(v.z) * sc[c0 + 5] + sh[c0 + 5]);
    float e6 = fmaxf(0.f, blo(v.w) * sc[c0 + 6] + sh[c0 + 6]);
    float e7 = fmaxf(0.f, bhi(v.w) * sc[c0 + 7] + sh[c0 + 7]);
    o.x = (unsigned int)f2b(e0) | ((unsigned int)f2b(e1) << 16);
    o.y = (unsigned int)f2b(e2) | ((unsigned int)f2b(e3) << 16);
    o.z = (unsigned int)f2b(e4) | ((unsigned int)f2b(e5) << 16);
    o.w = (unsigned int)f2b(e6) | ((unsigned int)f2b(e7) << 16);
    ((uint4*)ho)[i] = o;
}

// ---------------- host ----------------
extern "C" void kernel_launch(void* const* d_in, const int* in_sizes, int n_in,
                              void* d_out, int out_size, void* d_ws, size_t ws_size,
                              hipStream_t stream) {
    const float* x   = (const float*)d_in[0];
    const int* ei    = (const int*)d_in[1];     // [2, E] int32: row 0 = src, row 1 = dst
    const float* Wl0 = (const float*)d_in[2];
    const float* Wr0 = (const float*)d_in[3];
    const float* Wl1 = (const float*)d_in[4];
    const float* Wr1 = (const float*)d_in[5];
    const float* Wl2 = (const float*)d_in[6];
    const float* Wr2 = (const float*)d_in[7];
    const float* b2  = (const float*)d_in[8];
    const float* g0  = (const float*)d_in[9];
    const float* be0 = (const float*)d_in[10];
    const float* g1  = (const float*)d_in[11];
    const float* be1 = (const float*)d_in[12];

    char* ws = (char*)d_ws;
    size_t off = 0;
    auto alloc = [&](size_t bytes) -> void* {
        void* p = ws + off;
        off += (bytes + 4095) & ~(size_t)4095;
        return p;
    };

    const size_t NB16 = (size_t)N_NODES * 128 * 2;  // 25.6 MB bf16 feature buffer
    unsigned short* xb   = (unsigned short*)alloc(NB16);   // x in bf16; reused as h2
    unsigned short* h1   = (unsigned short*)alloc(NB16);
    unsigned short* mean = (unsigned short*)alloc(NB16);
    unsigned short* C    = (unsigned short*)alloc(NB16);   // pre-BN bf16
    unsigned int* cnt    = (unsigned int*)alloc((size_t)N_NODES * 4);
    unsigned int* rowptr = (unsigned int*)alloc((size_t)(N_NODES + 1) * 4);
    unsigned int* cursor = (unsigned int*)alloc((size_t)N_NODES * 4);
    int* srclist         = (int*)alloc((size_t)N_EDGES * 4);
    unsigned int* ebuf   = (unsigned int*)alloc((size_t)N_EDGES * 4);
    unsigned int* bhist  = (unsigned int*)alloc(8 * HB_BLOCKS * 4);
    unsigned int* bsum   = (unsigned int*)alloc(512 * 4);
    unsigned int* boff   = (unsigned int*)alloc(512 * 4);
    float* sums          = (float*)alloc(NBANK * 256 * 4);
    float* sc            = (float*)alloc(128 * 4);
    float* sh            = (float*)alloc(128 * 4);
    unsigned short* W0p  = (unsigned short*)alloc(8 * 8 * 64 * 8 * 2);
    unsigned short* W1p  = (unsigned short*)alloc(8 * 8 * 64 * 8 * 2);
    unsigned short* W2p  = (unsigned short*)alloc(3 * 8 * 64 * 8 * 2);
    unsigned short* h2   = xb;  // alias: xb dead after layer-0 GEMM

    const int* srcp = ei;
    const int* dstp = ei + N_EDGES;

    // ---- prep ----
    hipMemsetAsync(cnt, 0, (size_t)N_NODES * 4, stream);
    cvt_f32_bf16<<<12500, 256, 0, stream>>>(x, xb, N_NODES * 32);
    pack_w<<<(8 * 4096 + 255) / 256, 256, 0, stream>>>(Wl0, Wr0, W0p, 128, 8);
    pack_w<<<(8 * 4096 + 255) / 256, 256, 0, stream>>>(Wl1, Wr1, W1p, 128, 8);
    pack_w<<<(3 * 4096 + 255) / 256, 256, 0, stream>>>(Wl2, Wr2, W2p, 40, 3);

    // ---- CSR (two-level counting sort) ----
    hist_k<<<HB_BLOCKS, 256, 0, stream>>>(dstp, cnt, bhist);
    scan1<<<391, 256, 0, stream>>>(cnt, rowptr, bsum);
    scan2<<<1, 512, 0, stream>>>(bsum, boff, 391);
    scan3<<<391, 256, 0, stream>>>(rowptr, boff, cursor);
    bscan<<<1, 256, 0, stream>>>(bhist);
    bscatter<<<HB_BLOCKS, 256, 0, stream>>>(srcp, dstp, bhist, ebuf);
    cscatter<<<8 * CS_GPB, 256, 0, stream>>>(ebuf, rowptr, cursor, srclist);

    // ---- layer 0 ----
    agg_k<<<25000, 256, 0, stream>>>(xb, rowptr, srclist, mean);
    hipMemsetAsync(sums, 0, NBANK * 256 * 4, stream);
    gemm_k<8, 128, false, true, true><<<782, 256, 0, stream>>>(mean, xb, W0p, nullptr, C, sums);
    bn_finalize<<<1, 256, 0, stream>>>(sums, g0, be0, sc, sh);
    bn_apply<<<6250, 256, 0, stream>>>((const unsigned int*)C, sc, sh, h1);

    // ---- layer 1 ----
    agg_k<<<25000, 256, 0, stream>>>(h1, rowptr, srclist, mean);
    hipMemsetAsync(sums, 0, NBANK * 256 * 4, stream);
    gemm_k<8, 128, false, true, true><<<782, 256, 0, stream>>>(mean, h1, W1p, nullptr, C, sums);
    bn_finalize<<<1, 256, 0, stream>>>(sums, g1, be1, sc, sh);
    bn_apply<<<6250, 256, 0, stream>>>((const unsigned int*)C, sc, sh, h2);

    // ---- layer 2 (writes d_out, fp32 [N,40]) ----
    agg_k<<<25000, 256, 0, stream>>>(h2, rowptr, srclist, mean);
    gemm_k<3, 40, true, false, false><<<782, 256, 0, stream>>>(mean, h2, W2p, b2, d_out, nullptr);

    (void)in_sizes; (void)n_in; (void)out_size; (void)ws_size;
}

// Round 7
// 419.022 us; speedup vs baseline: 1.9675x; 1.0815x over previous
//
#include <hip/hip_runtime.h>
#include <hip/hip_bf16.h>

#define N_NODES 100000
#define N_EDGES 800000
#define EPS 1e-5f
#define NBANK 32
#define HB_BLOCKS 256
#define HB_PER 3125          // 256 * 3125 = 800000 exactly
#define CS_GPB 64            // cscatter blocks per coarse bucket
#define BUCKET_N 12500       // 8 * 12500 = 100000 exactly

typedef __attribute__((ext_vector_type(8))) short short8;
typedef __attribute__((ext_vector_type(4))) float floatx4;

__device__ __forceinline__ unsigned short f2b(float f) {
    unsigned int u = __float_as_uint(f);
    u = (u + 0x7fffu + ((u >> 16) & 1u)) >> 16;   // round-to-nearest-even
    return (unsigned short)u;
}
__device__ __forceinline__ float blo(unsigned int u) { return __uint_as_float(u << 16); }
__device__ __forceinline__ float bhi(unsigned int u) { return __uint_as_float(u & 0xffff0000u); }

// ---------------- elementwise convert fp32 -> bf16 (x input) ----------------
__global__ void cvt_f32_bf16(const float* __restrict__ x, unsigned short* __restrict__ o, int n4) {
    int i = blockIdx.x * blockDim.x + threadIdx.x;
    if (i >= n4) return;
    float4 v = ((const float4*)x)[i];
    ushort4 r;
    r.x = f2b(v.x); r.y = f2b(v.y); r.z = f2b(v.z); r.w = f2b(v.w);
    ((ushort4*)o)[i] = r;
}

// ---------------- pack [Wl;Wr] (K=256 x Hreal) into MFMA B-fragment order ----
__global__ void pack_w(const float* __restrict__ Wl, const float* __restrict__ Wr,
                       unsigned short* __restrict__ out, int Hreal, int NCT) {
    int tid = blockIdx.x * blockDim.x + threadIdx.x;
    int total = NCT * 8 * 64 * 8;
    if (tid >= total) return;
    int i = tid & 7;
    int lane = (tid >> 3) & 63;
    int q = tid >> 9;
    int c = q % NCT;
    int t = q / NCT;
    int k = t * 32 + (lane >> 4) * 8 + i;
    int n = c * 16 + (lane & 15);
    float v = 0.f;
    if (n < Hreal) v = (k < 128) ? Wl[k * Hreal + n] : Wr[(k - 128) * Hreal + n];
    out[tid] = f2b(v);
}

// ---------------- CSR build: two-level counting sort -------------------------
__global__ void __launch_bounds__(256) hist_k(const int* __restrict__ dst,
                                              unsigned int* __restrict__ cnt,
                                              unsigned int* __restrict__ bhist) {
    __shared__ unsigned int lh[8];
    if (threadIdx.x < 8) lh[threadIdx.x] = 0;
    __syncthreads();
    int start = blockIdx.x * HB_PER;
    for (int i = threadIdx.x; i < HB_PER; i += 256) {
        int d = dst[start + i];
        atomicAdd(&cnt[d], 1u);
        atomicAdd(&lh[(unsigned int)d / BUCKET_N], 1u);
    }
    __syncthreads();
    if (threadIdx.x < 8) bhist[threadIdx.x * HB_BLOCKS + blockIdx.x] = lh[threadIdx.x];
}

__global__ void bscan(unsigned int* __restrict__ A) {
    __shared__ unsigned int part[256];
    int t = threadIdx.x;
    unsigned int v[8];
    unsigned int s = 0;
#pragma unroll
    for (int i = 0; i < 8; i++) { v[i] = A[t * 8 + i]; s += v[i]; }
    part[t] = s; __syncthreads();
    for (int off = 1; off < 256; off <<= 1) {
        unsigned int add = (t >= off) ? part[t - off] : 0u;
        __syncthreads();
        part[t] += add;
        __syncthreads();
    }
    unsigned int base = part[t] - s;  // exclusive
#pragma unroll
    for (int i = 0; i < 8; i++) { unsigned int old = v[i]; A[t * 8 + i] = base; base += old; }
}

__global__ void __launch_bounds__(256) bscatter(const int* __restrict__ src,
                                                const int* __restrict__ dst,
                                                const unsigned int* __restrict__ boffs,
                                                unsigned int* __restrict__ ebuf) {
    __shared__ unsigned int cur[8];
    if (threadIdx.x < 8) cur[threadIdx.x] = boffs[threadIdx.x * HB_BLOCKS + blockIdx.x];
    __syncthreads();
    int start = blockIdx.x * HB_PER;
    for (int i = threadIdx.x; i < HB_PER; i += 256) {
        int d = dst[start + i];
        int s = src[start + i];
        unsigned int b = (unsigned int)d / BUCKET_N;
        unsigned int dl = (unsigned int)d - b * BUCKET_N;
        unsigned int pos = atomicAdd(&cur[b], 1u);
        ebuf[pos] = (unsigned int)s | (dl << 17);
    }
}

__global__ void __launch_bounds__(256) cscatter(const unsigned int* __restrict__ ebuf,
                                                const unsigned int* __restrict__ rowptr,
                                                unsigned int* __restrict__ cursor,
                                                int* __restrict__ srclist) {
    int g = blockIdx.x & 7;
    int gblk = blockIdx.x >> 3;
    unsigned int estart = rowptr[g * BUCKET_N];
    unsigned int eend = (g == 7) ? N_EDGES : rowptr[(g + 1) * BUCKET_N];
    unsigned int nume = eend - estart;
    unsigned int per = (nume + CS_GPB - 1) / CS_GPB;
    unsigned int s0 = estart + gblk * per;
    unsigned int s1 = s0 + per; if (s1 > eend) s1 = eend;
    unsigned int nodebase = g * BUCKET_N;
    for (unsigned int i = s0 + threadIdx.x; i < s1; i += 256) {
        unsigned int p = ebuf[i];
        unsigned int s = p & 0x1FFFFu;
        unsigned int node = nodebase + (p >> 17);
        unsigned int pos = atomicAdd(&cursor[node], 1u);
        srclist[pos] = (int)s;
    }
}

__global__ void scan1(const unsigned int* __restrict__ cnt, unsigned int* __restrict__ rowptr,
                      unsigned int* __restrict__ bsum) {
    __shared__ unsigned int sh[256];
    int t = threadIdx.x;
    int i = blockIdx.x * 256 + t;
    unsigned int v = (i < N_NODES) ? cnt[i] : 0u;
    sh[t] = v; __syncthreads();
    for (int off = 1; off < 256; off <<= 1) {
        unsigned int add = (t >= off) ? sh[t - off] : 0u;
        __syncthreads();
        sh[t] += add;
        __syncthreads();
    }
    if (i < N_NODES) rowptr[i] = sh[t] - v;  // exclusive within block
    if (t == 255) bsum[blockIdx.x] = sh[255];
}

__global__ void scan2(const unsigned int* __restrict__ bsum, unsigned int* __restrict__ boff, int nb) {
    __shared__ unsigned int sh[512];
    int t = threadIdx.x;
    unsigned int v = (t < nb) ? bsum[t] : 0u;
    sh[t] = v; __syncthreads();
    for (int off = 1; off < 512; off <<= 1) {
        unsigned int add = (t >= off) ? sh[t - off] : 0u;
        __syncthreads();
        sh[t] += add;
        __syncthreads();
    }
    if (t < nb) boff[t] = sh[t] - v;
}

__global__ void scan3(unsigned int* __restrict__ rowptr, const unsigned int* __restrict__ boff,
                      unsigned int* __restrict__ cursor) {
    int i = blockIdx.x * 256 + threadIdx.x;
    if (i < N_NODES) {
        unsigned int r = rowptr[i] + boff[blockIdx.x];
        rowptr[i] = r;
        cursor[i] = r;
    }
    if (i == N_NODES) rowptr[N_NODES] = N_EDGES;
}

// ---------------- mean aggregation ------------------------------------------
__global__ void __launch_bounds__(256) agg_k(const unsigned short* __restrict__ h,
                                             const unsigned int* __restrict__ rowptr,
                                             const int* __restrict__ srclist,
                                             unsigned short* __restrict__ mean) {
    int tid = blockIdx.x * 256 + threadIdx.x;
    int node = tid >> 6;
    int lane = tid & 63;
    if (node >= N_NODES) return;
    int g = lane >> 4, l = lane & 15;
    unsigned int b = rowptr[node], e = rowptr[node + 1];
    const uint4* hp = (const uint4*)h;
    float a0 = 0.f, a1 = 0.f, a2 = 0.f, a3 = 0.f, a4 = 0.f, a5 = 0.f, a6 = 0.f, a7 = 0.f;
    float b0 = 0.f, b1 = 0.f, b2 = 0.f, b3 = 0.f, b4 = 0.f, b5 = 0.f, b6 = 0.f, b7 = 0.f;
    unsigned int p = b;
    for (; p + 8 <= e; p += 8) {
        int s0 = srclist[p + g];
        int s1 = srclist[p + 4 + g];
        uint4 u0 = hp[(size_t)s0 * 16 + l];
        uint4 u1 = hp[(size_t)s1 * 16 + l];
        a0 += blo(u0.x); a1 += bhi(u0.x); a2 += blo(u0.y); a3 += bhi(u0.y);
        a4 += blo(u0.z); a5 += bhi(u0.z); a6 += blo(u0.w); a7 += bhi(u0.w);
        b0 += blo(u1.x); b1 += bhi(u1.x); b2 += blo(u1.y); b3 += bhi(u1.y);
        b4 += blo(u1.z); b5 += bhi(u1.z); b6 += blo(u1.w); b7 += bhi(u1.w);
    }
    if (p + 4 <= e) {
        int s0 = srclist[p + g];
        uint4 u0 = hp[(size_t)s0 * 16 + l];
        a0 += blo(u0.x); a1 += bhi(u0.x); a2 += blo(u0.y); a3 += bhi(u0.y);
        a4 += blo(u0.z); a5 += bhi(u0.z); a6 += blo(u0.w); a7 += bhi(u0.w);
        p += 4;
    }
    unsigned int rem = e - p;  // 0..3
    if ((unsigned int)g < rem) {
        int s1 = srclist[p + g];
        uint4 u1 = hp[(size_t)s1 * 16 + l];
        b0 += blo(u1.x); b1 += bhi(u1.x); b2 += blo(u1.y); b3 += bhi(u1.y);
        b4 += blo(u1.z); b5 += bhi(u1.z); b6 += blo(u1.w); b7 += bhi(u1.w);
    }
    unsigned int deg = e - b;
    float r = 1.0f / (float)(deg > 1u ? deg : 1u);
    float f0 = a0 + b0, f1 = a1 + b1, f2 = a2 + b2, f3 = a3 + b3;
    float f4 = a4 + b4, f5 = a5 + b5, f6 = a6 + b6, f7 = a7 + b7;
    f0 += __shfl_xor(f0, 16); f0 += __shfl_xor(f0, 32);
    f1 += __shfl_xor(f1, 16); f1 += __shfl_xor(f1, 32);
    f2 += __shfl_xor(f2, 16); f2 += __shfl_xor(f2, 32);
    f3 += __shfl_xor(f3, 16); f3 += __shfl_xor(f3, 32);
    f4 += __shfl_xor(f4, 16); f4 += __shfl_xor(f4, 32);
    f5 += __shfl_xor(f5, 16); f5 += __shfl_xor(f5, 32);
    f6 += __shfl_xor(f6, 16); f6 += __shfl_xor(f6, 32);
    f7 += __shfl_xor(f7, 16); f7 += __shfl_xor(f7, 32);
    if (g == 0) {
        uint4 o;
        o.x = (unsigned int)f2b(f0 * r) | ((unsigned int)f2b(f1 * r) << 16);
        o.y = (unsigned int)f2b(f2 * r) | ((unsigned int)f2b(f3 * r) << 16);
        o.z = (unsigned int)f2b(f4 * r) | ((unsigned int)f2b(f5 * r) << 16);
        o.w = (unsigned int)f2b(f6 * r) | ((unsigned int)f2b(f7 * r) << 16);
        ((uint4*)mean)[(size_t)node * 16 + l] = o;
    }
}

// ---------------- GEMM L0/L1: col-split for occupancy ------------------------
// (R6 post-mortem: 782-block gemm = 12 waves/CU theoretical, 17.6% achieved,
//  ~98% load-latency stall. Now: block = 64 rows x 128 cols, 4 waves = 2
//  row-slices x 2 col-halves -> 1563 blocks = 24.4 waves/CU; acc halves to
//  32 VGPRs; A-loads shared by col-half wave pair via L1.)
// Fused BN stats (32-bank atomics) + bf16 C output, as before.
__global__ void __launch_bounds__(256) gemm2_k(const unsigned short* __restrict__ meanb,
                                               const unsigned short* __restrict__ hb,
                                               const unsigned short* __restrict__ Bp,
                                               unsigned short* __restrict__ outb,
                                               float* __restrict__ sums) {
    __shared__ float lds_s[128];
    __shared__ float lds_s2[128];
    int wave = threadIdx.x >> 6;
    int lane = threadIdx.x & 63;
    int quad = lane >> 4;
    int l15 = lane & 15;
    int rowslice = wave & 1;
    int colhalf = wave >> 1;
    int rowbase = blockIdx.x * 64 + rowslice * 32;

    if (threadIdx.x < 128) { lds_s[threadIdx.x] = 0.f; lds_s2[threadIdx.x] = 0.f; }
    __syncthreads();

    floatx4 acc[2][4];
#pragma unroll
    for (int w = 0; w < 2; w++)
#pragma unroll
        for (int c = 0; c < 4; c++) acc[w][c] = (floatx4){0.f, 0.f, 0.f, 0.f};

    int r0 = rowbase + l15;       if (r0 > N_NODES - 1) r0 = N_NODES - 1;
    int r1 = rowbase + 16 + l15;  if (r1 > N_NODES - 1) r1 = N_NODES - 1;

#pragma unroll
    for (int t = 0; t < 8; t++) {
        const unsigned short* base = (t < 4) ? meanb : hb;
        int koff = (t & 3) * 32 + quad * 8;
        short8 a0 = *(const short8*)(base + (size_t)r0 * 128 + koff);
        short8 a1 = *(const short8*)(base + (size_t)r1 * 128 + koff);
#pragma unroll
        for (int c = 0; c < 4; c++) {
            int cidx = colhalf * 4 + c;
            short8 bf = *(const short8*)(Bp + ((size_t)(t * 8 + cidx) * 64 + lane) * 8);
            acc[0][c] = __builtin_amdgcn_mfma_f32_16x16x32_bf16(a0, bf, acc[0][c], 0, 0, 0);
            acc[1][c] = __builtin_amdgcn_mfma_f32_16x16x32_bf16(a1, bf, acc[1][c], 0, 0, 0);
        }
    }

#pragma unroll
    for (int c = 0; c < 4; c++) {
        int col = colhalf * 64 + c * 16 + l15;
        float s = 0.f, s2 = 0.f;
#pragma unroll
        for (int w = 0; w < 2; w++) {
#pragma unroll
            for (int r = 0; r < 4; r++) {
                int row = rowbase + w * 16 + quad * 4 + r;
                if (row < N_NODES) {
                    float v = acc[w][c][r];
                    outb[(size_t)row * 128 + col] = f2b(v);
                    s += v; s2 += v * v;
                }
            }
        }
        s += __shfl_xor(s, 16);  s += __shfl_xor(s, 32);
        s2 += __shfl_xor(s2, 16); s2 += __shfl_xor(s2, 32);
        if (quad == 0) {
            atomicAdd(&lds_s[col], s);
            atomicAdd(&lds_s2[col], s2);
        }
    }

    __syncthreads();
    if (threadIdx.x < 128) {
        int bank = blockIdx.x & (NBANK - 1);
        atomicAdd(&sums[bank * 256 + threadIdx.x], lds_s[threadIdx.x]);
        atomicAdd(&sums[bank * 256 + 128 + threadIdx.x], lds_s2[threadIdx.x]);
    }
}

// ---------------- GEMM L2: 64-row blocks, 4 row-slices, 40 cols, fp32+bias ---
__global__ void __launch_bounds__(256) gemm3_k(const unsigned short* __restrict__ meanb,
                                               const unsigned short* __restrict__ hb,
                                               const unsigned short* __restrict__ Bp,
                                               const float* __restrict__ bias,
                                               float* __restrict__ out) {
    int wave = threadIdx.x >> 6;
    int lane = threadIdx.x & 63;
    int quad = lane >> 4;
    int l15 = lane & 15;
    int rowbase = blockIdx.x * 64 + wave * 16;

    floatx4 acc[3];
#pragma unroll
    for (int c = 0; c < 3; c++) acc[c] = (floatx4){0.f, 0.f, 0.f, 0.f};

    int r0 = rowbase + l15;  if (r0 > N_NODES - 1) r0 = N_NODES - 1;

#pragma unroll
    for (int t = 0; t < 8; t++) {
        const unsigned short* base = (t < 4) ? meanb : hb;
        int koff = (t & 3) * 32 + quad * 8;
        short8 a0 = *(const short8*)(base + (size_t)r0 * 128 + koff);
#pragma unroll
        for (int c = 0; c < 3; c++) {
            short8 bf = *(const short8*)(Bp + ((size_t)(t * 3 + c) * 64 + lane) * 8);
            acc[c] = __builtin_amdgcn_mfma_f32_16x16x32_bf16(a0, bf, acc[c], 0, 0, 0);
        }
    }

#pragma unroll
    for (int c = 0; c < 3; c++) {
        int col = c * 16 + l15;
        if (col >= 40) continue;
#pragma unroll
        for (int r = 0; r < 4; r++) {
            int row = rowbase + quad * 4 + r;
            if (row < N_NODES) out[(size_t)row * 40 + col] = acc[c][r] + bias[col];
        }
    }
}

// ---------------- BN finalize (reduce 32 banks) ------------------------------
__global__ void bn_finalize(const float* __restrict__ sums, const float* __restrict__ g,
                            const float* __restrict__ be, float* __restrict__ sc,
                            float* __restrict__ sh) {
    __shared__ float lds[256];
    int t = threadIdx.x;
    float s = 0.f;
#pragma unroll 8
    for (int bk = 0; bk < NBANK; bk++) s += sums[bk * 256 + t];
    lds[t] = s;
    __syncthreads();
    if (t < 128) {
        float inv_n = 1.0f / (float)N_NODES;
        float mu = lds[t] * inv_n;
        float var = lds[128 + t] * inv_n - mu * mu;
        float sf = g[t] * rsqrtf(var + EPS);
        sc[t] = sf;
        sh[t] = be[t] - mu * sf;
    }
}

// ---------------- BN apply: bf16 in -> bf16 out, 8 elems/thread --------------
__global__ void bn_apply(const unsigned int* __restrict__ Cb, const float* __restrict__ sc,
                         const float* __restrict__ sh, unsigned short* __restrict__ ho) {
    int i = blockIdx.x * 256 + threadIdx.x;  // one uint4 = 8 bf16
    if (i >= N_NODES * 16) return;
    uint4 v = ((const uint4*)Cb)[i];
    int c0 = (i * 8) & 127;
    uint4 o;
    float e0 = fmaxf(0.f, blo(v.x) * sc[c0 + 0] + sh[c0 + 0]);
    float e1 = fmaxf(0.f, bhi(v.x) * sc[c0 + 1] + sh[c0 + 1]);
    float e2 = fmaxf(0.f, blo(v.y) * sc[c0 + 2] + sh[c0 + 2]);
    float e3 = fmaxf(0.f, bhi(v.y) * sc[c0 + 3] + sh[c0 + 3]);
    float e4 = fmaxf(0.f, blo(v.z) * sc[c0 + 4] + sh[c0 + 4]);
    float e5 = fmaxf(0.f, bhi(v.z) * sc[c0 + 5] + sh[c0 + 5]);
    float e6 = fmaxf(0.f, blo(v.w) * sc[c0 + 6] + sh[c0 + 6]);
    float e7 = fmaxf(0.f, bhi(v.w) * sc[c0 + 7] + sh[c0 + 7]);
    o.x = (unsigned int)f2b(e0) | ((unsigned int)f2b(e1) << 16);
    o.y = (unsigned int)f2b(e2) | ((unsigned int)f2b(e3) << 16);
    o.z = (unsigned int)f2b(e4) | ((unsigned int)f2b(e5) << 16);
    o.w = (unsigned int)f2b(e6) | ((unsigned int)f2b(e7) << 16);
    ((uint4*)ho)[i] = o;
}

// ---------------- host ----------------
extern "C" void kernel_launch(void* const* d_in, const int* in_sizes, int n_in,
                              void* d_out, int out_size, void* d_ws, size_t ws_size,
                              hipStream_t stream) {
    const float* x   = (const float*)d_in[0];
    const int* ei    = (const int*)d_in[1];     // [2, E] int32: row 0 = src, row 1 = dst
    const float* Wl0 = (const float*)d_in[2];
    const float* Wr0 = (const float*)d_in[3];
    const float* Wl1 = (const float*)d_in[4];
    const float* Wr1 = (const float*)d_in[5];
    const float* Wl2 = (const float*)d_in[6];
    const float* Wr2 = (const float*)d_in[7];
    const float* b2  = (const float*)d_in[8];
    const float* g0  = (const float*)d_in[9];
    const float* be0 = (const float*)d_in[10];
    const float* g1  = (const float*)d_in[11];
    const float* be1 = (const float*)d_in[12];

    char* ws = (char*)d_ws;
    size_t off = 0;
    auto alloc = [&](size_t bytes) -> void* {
        void* p = ws + off;
        off += (bytes + 4095) & ~(size_t)4095;
        return p;
    };

    const size_t NB16 = (size_t)N_NODES * 128 * 2;  // 25.6 MB bf16 feature buffer
    unsigned short* xb   = (unsigned short*)alloc(NB16);   // x in bf16; reused as h2
    unsigned short* h1   = (unsigned short*)alloc(NB16);
    unsigned short* mean = (unsigned short*)alloc(NB16);
    unsigned short* C    = (unsigned short*)alloc(NB16);   // pre-BN bf16
    unsigned int* cnt    = (unsigned int*)alloc((size_t)N_NODES * 4);
    unsigned int* rowptr = (unsigned int*)alloc((size_t)(N_NODES + 1) * 4);
    unsigned int* cursor = (unsigned int*)alloc((size_t)N_NODES * 4);
    int* srclist         = (int*)alloc((size_t)N_EDGES * 4);
    unsigned int* ebuf   = (unsigned int*)alloc((size_t)N_EDGES * 4);
    unsigned int* bhist  = (unsigned int*)alloc(8 * HB_BLOCKS * 4);
    unsigned int* bsum   = (unsigned int*)alloc(512 * 4);
    unsigned int* boff   = (unsigned int*)alloc(512 * 4);
    float* sums0         = (float*)alloc(NBANK * 256 * 4);   // contiguous with sums1
    float* sums1         = (float*)alloc(NBANK * 256 * 4);
    float* sc            = (float*)alloc(128 * 4);
    float* sh            = (float*)alloc(128 * 4);
    unsigned short* W0p  = (unsigned short*)alloc(8 * 8 * 64 * 8 * 2);
    unsigned short* W1p  = (unsigned short*)alloc(8 * 8 * 64 * 8 * 2);
    unsigned short* W2p  = (unsigned short*)alloc(3 * 8 * 64 * 8 * 2);
    unsigned short* h2   = xb;  // alias: xb dead after layer-0 GEMM

    const int* srcp = ei;
    const int* dstp = ei + N_EDGES;

    // ---- prep (both BN sums buffers zeroed up front; none mid-pipeline) ----
    hipMemsetAsync(cnt, 0, (size_t)N_NODES * 4, stream);
    hipMemsetAsync(sums0, 0, (size_t)2 * NBANK * 256 * 4, stream);  // sums0+sums1
    cvt_f32_bf16<<<12500, 256, 0, stream>>>(x, xb, N_NODES * 32);
    pack_w<<<(8 * 4096 + 255) / 256, 256, 0, stream>>>(Wl0, Wr0, W0p, 128, 8);
    pack_w<<<(8 * 4096 + 255) / 256, 256, 0, stream>>>(Wl1, Wr1, W1p, 128, 8);
    pack_w<<<(3 * 4096 + 255) / 256, 256, 0, stream>>>(Wl2, Wr2, W2p, 40, 3);

    // ---- CSR (two-level counting sort) ----
    hist_k<<<HB_BLOCKS, 256, 0, stream>>>(dstp, cnt, bhist);
    scan1<<<391, 256, 0, stream>>>(cnt, rowptr, bsum);
    scan2<<<1, 512, 0, stream>>>(bsum, boff, 391);
    scan3<<<391, 256, 0, stream>>>(rowptr, boff, cursor);
    bscan<<<1, 256, 0, stream>>>(bhist);
    bscatter<<<HB_BLOCKS, 256, 0, stream>>>(srcp, dstp, bhist, ebuf);
    cscatter<<<8 * CS_GPB, 256, 0, stream>>>(ebuf, rowptr, cursor, srclist);

    // ---- layer 0 ----
    agg_k<<<25000, 256, 0, stream>>>(xb, rowptr, srclist, mean);
    gemm2_k<<<1563, 256, 0, stream>>>(mean, xb, W0p, C, sums0);
    bn_finalize<<<1, 256, 0, stream>>>(sums0, g0, be0, sc, sh);
    bn_apply<<<6250, 256, 0, stream>>>((const unsigned int*)C, sc, sh, h1);

    // ---- layer 1 ----
    agg_k<<<25000, 256, 0, stream>>>(h1, rowptr, srclist, mean);
    gemm2_k<<<1563, 256, 0, stream>>>(mean, h1, W1p, C, sums1);
    bn_finalize<<<1, 256, 0, stream>>>(sums1, g1, be1, sc, sh);
    bn_apply<<<6250, 256, 0, stream>>>((const unsigned int*)C, sc, sh, h2);

    // ---- layer 2 (writes d_out, fp32 [N,40]) ----
    agg_k<<<25000, 256, 0, stream>>>(h2, rowptr, srclist, mean);
    gemm3_k<<<1563, 256, 0, stream>>>(mean, h2, W2p, b2, (float*)d_out);

    (void)in_sizes; (void)n_in; (void)out_size; (void)ws_size;
}

// Round 8
// 401.058 us; speedup vs baseline: 2.0556x; 1.0448x over previous
//
#include <hip/hip_runtime.h>
#include <hip/hip_bf16.h>

#define N_NODES 100000
#define N_EDGES 800000
#define EPS 1e-5f
#define NBANK 32
#define HB_BLOCKS 256
#define HB_PER 3125          // 256 * 3125 = 800000 exactly
#define CS_GPB 64            // cscatter blocks per coarse bucket
#define BUCKET_N 12500       // 8 * 12500 = 100000 exactly
#define MROW 68              // LDS mean row stride in dwords (64 + 4 pad: 2-way banks)

typedef __attribute__((ext_vector_type(8))) short short8;
typedef __attribute__((ext_vector_type(4))) float floatx4;

__device__ __forceinline__ unsigned short f2b(float f) {
    unsigned int u = __float_as_uint(f);
    u = (u + 0x7fffu + ((u >> 16) & 1u)) >> 16;   // round-to-nearest-even
    return (unsigned short)u;
}
__device__ __forceinline__ float blo(unsigned int u) { return __uint_as_float(u << 16); }
__device__ __forceinline__ float bhi(unsigned int u) { return __uint_as_float(u & 0xffff0000u); }

// ---------------- elementwise convert fp32 -> bf16 (x input) ----------------
__global__ void cvt_f32_bf16(const float* __restrict__ x, unsigned short* __restrict__ o, int n4) {
    int i = blockIdx.x * blockDim.x + threadIdx.x;
    if (i >= n4) return;
    float4 v = ((const float4*)x)[i];
    ushort4 r;
    r.x = f2b(v.x); r.y = f2b(v.y); r.z = f2b(v.z); r.w = f2b(v.w);
    ((ushort4*)o)[i] = r;
}

// ---------------- pack [Wl;Wr] (K=256 x Hreal) into MFMA B-fragment order ----
__global__ void pack_w(const float* __restrict__ Wl, const float* __restrict__ Wr,
                       unsigned short* __restrict__ out, int Hreal, int NCT) {
    int tid = blockIdx.x * blockDim.x + threadIdx.x;
    int total = NCT * 8 * 64 * 8;
    if (tid >= total) return;
    int i = tid & 7;
    int lane = (tid >> 3) & 63;
    int q = tid >> 9;
    int c = q % NCT;
    int t = q / NCT;
    int k = t * 32 + (lane >> 4) * 8 + i;
    int n = c * 16 + (lane & 15);
    float v = 0.f;
    if (n < Hreal) v = (k < 128) ? Wl[k * Hreal + n] : Wr[(k - 128) * Hreal + n];
    out[tid] = f2b(v);
}

// ---------------- CSR build: two-level counting sort -------------------------
__global__ void __launch_bounds__(256) hist_k(const int* __restrict__ dst,
                                              unsigned int* __restrict__ cnt,
                                              unsigned int* __restrict__ bhist) {
    __shared__ unsigned int lh[8];
    if (threadIdx.x < 8) lh[threadIdx.x] = 0;
    __syncthreads();
    int start = blockIdx.x * HB_PER;
    for (int i = threadIdx.x; i < HB_PER; i += 256) {
        int d = dst[start + i];
        atomicAdd(&cnt[d], 1u);
        atomicAdd(&lh[(unsigned int)d / BUCKET_N], 1u);
    }
    __syncthreads();
    if (threadIdx.x < 8) bhist[threadIdx.x * HB_BLOCKS + blockIdx.x] = lh[threadIdx.x];
}

__global__ void bscan(unsigned int* __restrict__ A) {
    __shared__ unsigned int part[256];
    int t = threadIdx.x;
    unsigned int v[8];
    unsigned int s = 0;
#pragma unroll
    for (int i = 0; i < 8; i++) { v[i] = A[t * 8 + i]; s += v[i]; }
    part[t] = s; __syncthreads();
    for (int off = 1; off < 256; off <<= 1) {
        unsigned int add = (t >= off) ? part[t - off] : 0u;
        __syncthreads();
        part[t] += add;
        __syncthreads();
    }
    unsigned int base = part[t] - s;  // exclusive
#pragma unroll
    for (int i = 0; i < 8; i++) { unsigned int old = v[i]; A[t * 8 + i] = base; base += old; }
}

__global__ void __launch_bounds__(256) bscatter(const int* __restrict__ src,
                                                const int* __restrict__ dst,
                                                const unsigned int* __restrict__ boffs,
                                                unsigned int* __restrict__ ebuf) {
    __shared__ unsigned int cur[8];
    if (threadIdx.x < 8) cur[threadIdx.x] = boffs[threadIdx.x * HB_BLOCKS + blockIdx.x];
    __syncthreads();
    int start = blockIdx.x * HB_PER;
    for (int i = threadIdx.x; i < HB_PER; i += 256) {
        int d = dst[start + i];
        int s = src[start + i];
        unsigned int b = (unsigned int)d / BUCKET_N;
        unsigned int dl = (unsigned int)d - b * BUCKET_N;
        unsigned int pos = atomicAdd(&cur[b], 1u);
        ebuf[pos] = (unsigned int)s | (dl << 17);
    }
}

__global__ void __launch_bounds__(256) cscatter(const unsigned int* __restrict__ ebuf,
                                                const unsigned int* __restrict__ rowptr,
                                                unsigned int* __restrict__ cursor,
                                                int* __restrict__ srclist) {
    int g = blockIdx.x & 7;
    int gblk = blockIdx.x >> 3;
    unsigned int estart = rowptr[g * BUCKET_N];
    unsigned int eend = (g == 7) ? N_EDGES : rowptr[(g + 1) * BUCKET_N];
    unsigned int nume = eend - estart;
    unsigned int per = (nume + CS_GPB - 1) / CS_GPB;
    unsigned int s0 = estart + gblk * per;
    unsigned int s1 = s0 + per; if (s1 > eend) s1 = eend;
    unsigned int nodebase = g * BUCKET_N;
    for (unsigned int i = s0 + threadIdx.x; i < s1; i += 256) {
        unsigned int p = ebuf[i];
        unsigned int s = p & 0x1FFFFu;
        unsigned int node = nodebase + (p >> 17);
        unsigned int pos = atomicAdd(&cursor[node], 1u);
        srclist[pos] = (int)s;
    }
}

__global__ void scan1(const unsigned int* __restrict__ cnt, unsigned int* __restrict__ rowptr,
                      unsigned int* __restrict__ bsum) {
    __shared__ unsigned int sh[256];
    int t = threadIdx.x;
    int i = blockIdx.x * 256 + t;
    unsigned int v = (i < N_NODES) ? cnt[i] : 0u;
    sh[t] = v; __syncthreads();
    for (int off = 1; off < 256; off <<= 1) {
        unsigned int add = (t >= off) ? sh[t - off] : 0u;
        __syncthreads();
        sh[t] += add;
        __syncthreads();
    }
    if (i < N_NODES) rowptr[i] = sh[t] - v;  // exclusive within block
    if (t == 255) bsum[blockIdx.x] = sh[255];
}

__global__ void scan2(const unsigned int* __restrict__ bsum, unsigned int* __restrict__ boff, int nb) {
    __shared__ unsigned int sh[512];
    int t = threadIdx.x;
    unsigned int v = (t < nb) ? bsum[t] : 0u;
    sh[t] = v; __syncthreads();
    for (int off = 1; off < 512; off <<= 1) {
        unsigned int add = (t >= off) ? sh[t - off] : 0u;
        __syncthreads();
        sh[t] += add;
        __syncthreads();
    }
    if (t < nb) boff[t] = sh[t] - v;
}

__global__ void scan3(unsigned int* __restrict__ rowptr, const unsigned int* __restrict__ boff,
                      unsigned int* __restrict__ cursor) {
    int i = blockIdx.x * 256 + threadIdx.x;
    if (i < N_NODES) {
        unsigned int r = rowptr[i] + boff[blockIdx.x];
        rowptr[i] = r;
        cursor[i] = r;
    }
    if (i == N_NODES) rowptr[N_NODES] = N_EDGES;
}

// ---------------- phase-1 helper: aggregate 16 nodes/wave into LDS -----------
// wave = 4 groups x 16 lanes; group handles 4 nodes sequentially; lane owns a
// 16 B slice of the row -> no cross-lane reduce, epilogue = scale+pack+1 write.
__device__ __forceinline__ void agg_phase(const unsigned short* __restrict__ hb,
                                          const unsigned int* __restrict__ rowptr,
                                          const int* __restrict__ srclist,
                                          unsigned int* __restrict__ smean,
                                          int wave, int g, int l, int blockrow) {
    const uint4* hp = (const uint4*)hb;
#pragma unroll
    for (int it = 0; it < 4; ++it) {
        int nl = wave * 16 + it * 4 + g;
        int node = blockrow + nl;
        float f0 = 0.f, f1 = 0.f, f2 = 0.f, f3 = 0.f, f4 = 0.f, f5 = 0.f, f6 = 0.f, f7 = 0.f;
        if (node < N_NODES) {
            unsigned int b = rowptr[node], e = rowptr[node + 1];
            unsigned int p = b;
            for (; p + 2 <= e; p += 2) {
                int s0 = srclist[p];
                int s1 = srclist[p + 1];
                uint4 u0 = hp[(size_t)s0 * 16 + l];
                uint4 u1 = hp[(size_t)s1 * 16 + l];
                f0 += blo(u0.x); f1 += bhi(u0.x); f2 += blo(u0.y); f3 += bhi(u0.y);
                f4 += blo(u0.z); f5 += bhi(u0.z); f6 += blo(u0.w); f7 += bhi(u0.w);
                f0 += blo(u1.x); f1 += bhi(u1.x); f2 += blo(u1.y); f3 += bhi(u1.y);
                f4 += blo(u1.z); f5 += bhi(u1.z); f6 += blo(u1.w); f7 += bhi(u1.w);
            }
            if (p < e) {
                int s0 = srclist[p];
                uint4 u0 = hp[(size_t)s0 * 16 + l];
                f0 += blo(u0.x); f1 += bhi(u0.x); f2 += blo(u0.y); f3 += bhi(u0.y);
                f4 += blo(u0.z); f5 += bhi(u0.z); f6 += blo(u0.w); f7 += bhi(u0.w);
            }
            unsigned int deg = e - b;
            float r = 1.0f / (float)(deg > 1u ? deg : 1u);
            f0 *= r; f1 *= r; f2 *= r; f3 *= r; f4 *= r; f5 *= r; f6 *= r; f7 *= r;
        }
        uint4 o;
        o.x = (unsigned int)f2b(f0) | ((unsigned int)f2b(f1) << 16);
        o.y = (unsigned int)f2b(f2) | ((unsigned int)f2b(f3) << 16);
        o.z = (unsigned int)f2b(f4) | ((unsigned int)f2b(f5) << 16);
        o.w = (unsigned int)f2b(f6) | ((unsigned int)f2b(f7) << 16);
        *(uint4*)&smean[nl * MROW + l * 4] = o;
    }
}

// ---------------- fused agg + GEMM L0/L1 + BN stats + bf16 C -----------------
// (R7 post-mortem: agg_k 3x41 us, VALU-bound w/ 34-inst/node epilogue + mean
//  global round-trip. Fused: block aggregates its 64 rows into LDS (phase 1),
//  then col-split MFMA loop reads A mean-half from LDS (phase 2).)
__global__ void __launch_bounds__(256) gemm2f_k(const unsigned short* __restrict__ hb,
                                                const unsigned int* __restrict__ rowptr,
                                                const int* __restrict__ srclist,
                                                const unsigned short* __restrict__ Bp,
                                                unsigned short* __restrict__ outb,
                                                float* __restrict__ sums) {
    __shared__ unsigned int smean[64 * MROW];
    __shared__ float lds_s[128];
    __shared__ float lds_s2[128];
    int wave = threadIdx.x >> 6;
    int lane = threadIdx.x & 63;
    int quad = lane >> 4;
    int l15 = lane & 15;
    int blockrow = blockIdx.x * 64;

    if (threadIdx.x < 128) { lds_s[threadIdx.x] = 0.f; lds_s2[threadIdx.x] = 0.f; }

    // phase 1: aggregate 64 means into LDS
    agg_phase(hb, rowptr, srclist, smean, wave, quad, l15, blockrow);
    __syncthreads();

    // phase 2: col-split MFMA (2 row-slices x 2 col-halves)
    int rowslice = wave & 1;
    int colhalf = wave >> 1;
    int rowbase = blockrow + rowslice * 32;

    floatx4 acc[2][4];
#pragma unroll
    for (int w = 0; w < 2; w++)
#pragma unroll
        for (int c = 0; c < 4; c++) acc[w][c] = (floatx4){0.f, 0.f, 0.f, 0.f};

    int rl0 = rowslice * 32 + l15;          // LDS mean rows
    int rl1 = rl0 + 16;
    int r0 = rowbase + l15;       if (r0 > N_NODES - 1) r0 = N_NODES - 1;
    int r1 = rowbase + 16 + l15;  if (r1 > N_NODES - 1) r1 = N_NODES - 1;

#pragma unroll
    for (int t = 0; t < 8; t++) {
        short8 a0, a1;
        if (t < 4) {
            int doff = t * 16 + quad * 4;
            a0 = *(const short8*)&smean[rl0 * MROW + doff];
            a1 = *(const short8*)&smean[rl1 * MROW + doff];
        } else {
            int koff = (t & 3) * 32 + quad * 8;
            a0 = *(const short8*)(hb + (size_t)r0 * 128 + koff);
            a1 = *(const short8*)(hb + (size_t)r1 * 128 + koff);
        }
#pragma unroll
        for (int c = 0; c < 4; c++) {
            int cidx = colhalf * 4 + c;
            short8 bf = *(const short8*)(Bp + ((size_t)(t * 8 + cidx) * 64 + lane) * 8);
            acc[0][c] = __builtin_amdgcn_mfma_f32_16x16x32_bf16(a0, bf, acc[0][c], 0, 0, 0);
            acc[1][c] = __builtin_amdgcn_mfma_f32_16x16x32_bf16(a1, bf, acc[1][c], 0, 0, 0);
        }
    }

#pragma unroll
    for (int c = 0; c < 4; c++) {
        int col = colhalf * 64 + c * 16 + l15;
        float s = 0.f, s2 = 0.f;
#pragma unroll
        for (int w = 0; w < 2; w++) {
#pragma unroll
            for (int r = 0; r < 4; r++) {
                int row = rowbase + w * 16 + quad * 4 + r;
                if (row < N_NODES) {
                    float v = acc[w][c][r];
                    outb[(size_t)row * 128 + col] = f2b(v);
                    s += v; s2 += v * v;
                }
            }
        }
        s += __shfl_xor(s, 16);  s += __shfl_xor(s, 32);
        s2 += __shfl_xor(s2, 16); s2 += __shfl_xor(s2, 32);
        if (quad == 0) {
            atomicAdd(&lds_s[col], s);
            atomicAdd(&lds_s2[col], s2);
        }
    }

    __syncthreads();
    if (threadIdx.x < 128) {
        int bank = blockIdx.x & (NBANK - 1);
        atomicAdd(&sums[bank * 256 + threadIdx.x], lds_s[threadIdx.x]);
        atomicAdd(&sums[bank * 256 + 128 + threadIdx.x], lds_s2[threadIdx.x]);
    }
}

// ---------------- fused agg + GEMM L2 (40 cols, bias, fp32 out) --------------
__global__ void __launch_bounds__(256) gemm3f_k(const unsigned short* __restrict__ hb,
                                                const unsigned int* __restrict__ rowptr,
                                                const int* __restrict__ srclist,
                                                const unsigned short* __restrict__ Bp,
                                                const float* __restrict__ bias,
                                                float* __restrict__ out) {
    __shared__ unsigned int smean[64 * MROW];
    int wave = threadIdx.x >> 6;
    int lane = threadIdx.x & 63;
    int quad = lane >> 4;
    int l15 = lane & 15;
    int blockrow = blockIdx.x * 64;

    agg_phase(hb, rowptr, srclist, smean, wave, quad, l15, blockrow);
    __syncthreads();

    int rowbase = blockrow + wave * 16;
    floatx4 acc[3];
#pragma unroll
    for (int c = 0; c < 3; c++) acc[c] = (floatx4){0.f, 0.f, 0.f, 0.f};

    int rl0 = wave * 16 + l15;
    int r0 = rowbase + l15;  if (r0 > N_NODES - 1) r0 = N_NODES - 1;

#pragma unroll
    for (int t = 0; t < 8; t++) {
        short8 a0;
        if (t < 4) {
            a0 = *(const short8*)&smean[rl0 * MROW + t * 16 + quad * 4];
        } else {
            int koff = (t & 3) * 32 + quad * 8;
            a0 = *(const short8*)(hb + (size_t)r0 * 128 + koff);
        }
#pragma unroll
        for (int c = 0; c < 3; c++) {
            short8 bf = *(const short8*)(Bp + ((size_t)(t * 3 + c) * 64 + lane) * 8);
            acc[c] = __builtin_amdgcn_mfma_f32_16x16x32_bf16(a0, bf, acc[c], 0, 0, 0);
        }
    }

#pragma unroll
    for (int c = 0; c < 3; c++) {
        int col = c * 16 + l15;
        if (col >= 40) continue;
#pragma unroll
        for (int r = 0; r < 4; r++) {
            int row = rowbase + quad * 4 + r;
            if (row < N_NODES) out[(size_t)row * 40 + col] = acc[c][r] + bias[col];
        }
    }
}

// ---------------- BN finalize (reduce 32 banks) ------------------------------
__global__ void bn_finalize(const float* __restrict__ sums, const float* __restrict__ g,
                            const float* __restrict__ be, float* __restrict__ sc,
                            float* __restrict__ sh) {
    __shared__ float lds[256];
    int t = threadIdx.x;
    float s = 0.f;
#pragma unroll 8
    for (int bk = 0; bk < NBANK; bk++) s += sums[bk * 256 + t];
    lds[t] = s;
    __syncthreads();
    if (t < 128) {
        float inv_n = 1.0f / (float)N_NODES;
        float mu = lds[t] * inv_n;
        float var = lds[128 + t] * inv_n - mu * mu;
        float sf = g[t] * rsqrtf(var + EPS);
        sc[t] = sf;
        sh[t] = be[t] - mu * sf;
    }
}

// ---------------- BN apply: bf16 in -> bf16 out, 8 elems/thread --------------
__global__ void bn_apply(const unsigned int* __restrict__ Cb, const float* __restrict__ sc,
                         const float* __restrict__ sh, unsigned short* __restrict__ ho) {
    int i = blockIdx.x * 256 + threadIdx.x;  // one uint4 = 8 bf16
    if (i >= N_NODES * 16) return;
    uint4 v = ((const uint4*)Cb)[i];
    int c0 = (i * 8) & 127;
    uint4 o;
    float e0 = fmaxf(0.f, blo(v.x) * sc[c0 + 0] + sh[c0 + 0]);
    float e1 = fmaxf(0.f, bhi(v.x) * sc[c0 + 1] + sh[c0 + 1]);
    float e2 = fmaxf(0.f, blo(v.y) * sc[c0 + 2] + sh[c0 + 2]);
    float e3 = fmaxf(0.f, bhi(v.y) * sc[c0 + 3] + sh[c0 + 3]);
    float e4 = fmaxf(0.f, blo(v.z) * sc[c0 + 4] + sh[c0 + 4]);
    float e5 = fmaxf(0.f, bhi(v.z) * sc[c0 + 5] + sh[c0 + 5]);
    float e6 = fmaxf(0.f, blo(v.w) * sc[c0 + 6] + sh[c0 + 6]);
    float e7 = fmaxf(0.f, bhi(v.w) * sc[c0 + 7] + sh[c0 + 7]);
    o.x = (unsigned int)f2b(e0) | ((unsigned int)f2b(e1) << 16);
    o.y = (unsigned int)f2b(e2) | ((unsigned int)f2b(e3) << 16);
    o.z = (unsigned int)f2b(e4) | ((unsigned int)f2b(e5) << 16);
    o.w = (unsigned int)f2b(e6) | ((unsigned int)f2b(e7) << 16);
    ((uint4*)ho)[i] = o;
}

// ---------------- host ----------------
extern "C" void kernel_launch(void* const* d_in, const int* in_sizes, int n_in,
                              void* d_out, int out_size, void* d_ws, size_t ws_size,
                              hipStream_t stream) {
    const float* x   = (const float*)d_in[0];
    const int* ei    = (const int*)d_in[1];     // [2, E] int32: row 0 = src, row 1 = dst
    const float* Wl0 = (const float*)d_in[2];
    const float* Wr0 = (const float*)d_in[3];
    const float* Wl1 = (const float*)d_in[4];
    const float* Wr1 = (const float*)d_in[5];
    const float* Wl2 = (const float*)d_in[6];
    const float* Wr2 = (const float*)d_in[7];
    const float* b2  = (const float*)d_in[8];
    const float* g0  = (const float*)d_in[9];
    const float* be0 = (const float*)d_in[10];
    const float* g1  = (const float*)d_in[11];
    const float* be1 = (const float*)d_in[12];

    char* ws = (char*)d_ws;
    size_t off = 0;
    auto alloc = [&](size_t bytes) -> void* {
        void* p = ws + off;
        off += (bytes + 4095) & ~(size_t)4095;
        return p;
    };

    const size_t NB16 = (size_t)N_NODES * 128 * 2;  // 25.6 MB bf16 feature buffer
    unsigned short* xb   = (unsigned short*)alloc(NB16);   // x in bf16; reused as h2
    unsigned short* h1   = (unsigned short*)alloc(NB16);
    unsigned short* C    = (unsigned short*)alloc(NB16);   // pre-BN bf16
    unsigned int* cnt    = (unsigned int*)alloc((size_t)N_NODES * 4);
    unsigned int* rowptr = (unsigned int*)alloc((size_t)(N_NODES + 1) * 4);
    unsigned int* cursor = (unsigned int*)alloc((size_t)N_NODES * 4);
    int* srclist         = (int*)alloc((size_t)N_EDGES * 4);
    unsigned int* ebuf   = (unsigned int*)alloc((size_t)N_EDGES * 4);
    unsigned int* bhist  = (unsigned int*)alloc(8 * HB_BLOCKS * 4);
    unsigned int* bsum   = (unsigned int*)alloc(512 * 4);
    unsigned int* boff   = (unsigned int*)alloc(512 * 4);
    float* sums0         = (float*)alloc(NBANK * 256 * 4);   // contiguous with sums1
    float* sums1         = (float*)alloc(NBANK * 256 * 4);
    float* sc            = (float*)alloc(128 * 4);
    float* sh            = (float*)alloc(128 * 4);
    unsigned short* W0p  = (unsigned short*)alloc(8 * 8 * 64 * 8 * 2);
    unsigned short* W1p  = (unsigned short*)alloc(8 * 8 * 64 * 8 * 2);
    unsigned short* W2p  = (unsigned short*)alloc(3 * 8 * 64 * 8 * 2);
    unsigned short* h2   = xb;  // alias: xb dead after layer-0 GEMM

    const int* srcp = ei;
    const int* dstp = ei + N_EDGES;

    // ---- prep (both BN sums buffers zeroed up front; none mid-pipeline) ----
    hipMemsetAsync(cnt, 0, (size_t)N_NODES * 4, stream);
    hipMemsetAsync(sums0, 0, (size_t)2 * NBANK * 256 * 4, stream);  // sums0+sums1
    cvt_f32_bf16<<<12500, 256, 0, stream>>>(x, xb, N_NODES * 32);
    pack_w<<<(8 * 4096 + 255) / 256, 256, 0, stream>>>(Wl0, Wr0, W0p, 128, 8);
    pack_w<<<(8 * 4096 + 255) / 256, 256, 0, stream>>>(Wl1, Wr1, W1p, 128, 8);
    pack_w<<<(3 * 4096 + 255) / 256, 256, 0, stream>>>(Wl2, Wr2, W2p, 40, 3);

    // ---- CSR (two-level counting sort) ----
    hist_k<<<HB_BLOCKS, 256, 0, stream>>>(dstp, cnt, bhist);
    scan1<<<391, 256, 0, stream>>>(cnt, rowptr, bsum);
    scan2<<<1, 512, 0, stream>>>(bsum, boff, 391);
    scan3<<<391, 256, 0, stream>>>(rowptr, boff, cursor);
    bscan<<<1, 256, 0, stream>>>(bhist);
    bscatter<<<HB_BLOCKS, 256, 0, stream>>>(srcp, dstp, bhist, ebuf);
    cscatter<<<8 * CS_GPB, 256, 0, stream>>>(ebuf, rowptr, cursor, srclist);

    // ---- layer 0 (fused agg+gemm) ----
    gemm2f_k<<<1563, 256, 0, stream>>>(xb, rowptr, srclist, W0p, C, sums0);
    bn_finalize<<<1, 256, 0, stream>>>(sums0, g0, be0, sc, sh);
    bn_apply<<<6250, 256, 0, stream>>>((const unsigned int*)C, sc, sh, h1);

    // ---- layer 1 ----
    gemm2f_k<<<1563, 256, 0, stream>>>(h1, rowptr, srclist, W1p, C, sums1);
    bn_finalize<<<1, 256, 0, stream>>>(sums1, g1, be1, sc, sh);
    bn_apply<<<6250, 256, 0, stream>>>((const unsigned int*)C, sc, sh, h2);

    // ---- layer 2 (writes d_out, fp32 [N,40]) ----
    gemm3f_k<<<1563, 256, 0, stream>>>(h2, rowptr, srclist, W2p, b2, (float*)d_out);

    (void)in_sizes; (void)n_in; (void)out_size; (void)ws_size;
}

// Round 9
// 382.923 us; speedup vs baseline: 2.1530x; 1.0474x over previous
//
#include <hip/hip_runtime.h>
#include <hip/hip_bf16.h>

#define N_NODES 100000
#define N_EDGES 800000
#define EPS 1e-5f
#define NBANK 32
#define HB_BLOCKS 256
#define HB_PER 3125          // 256 * 3125 = 800000 exactly
#define CS_GPB 64            // cscatter blocks per coarse bucket
#define BUCKET_N 12500       // 8 * 12500 = 100000 exactly
#define MROW 68              // LDS mean row stride in dwords (64 + 4 pad)

typedef __attribute__((ext_vector_type(8))) short short8;
typedef __attribute__((ext_vector_type(4))) float floatx4;

__device__ __forceinline__ unsigned short f2b(float f) {
    unsigned int u = __float_as_uint(f);
    u = (u + 0x7fffu + ((u >> 16) & 1u)) >> 16;   // round-to-nearest-even
    return (unsigned short)u;
}
__device__ __forceinline__ float blo(unsigned int u) { return __uint_as_float(u << 16); }
__device__ __forceinline__ float bhi(unsigned int u) { return __uint_as_float(u & 0xffff0000u); }

// ---------------- elementwise convert fp32 -> bf16 (x input) ----------------
__global__ void cvt_f32_bf16(const float* __restrict__ x, unsigned short* __restrict__ o, int n4) {
    int i = blockIdx.x * blockDim.x + threadIdx.x;
    if (i >= n4) return;
    float4 v = ((const float4*)x)[i];
    ushort4 r;
    r.x = f2b(v.x); r.y = f2b(v.y); r.z = f2b(v.z); r.w = f2b(v.w);
    ((ushort4*)o)[i] = r;
}

// ---------------- pack [Wl;Wr] (K=256 x Hreal) into MFMA B-fragment order ----
__global__ void pack_w(const float* __restrict__ Wl, const float* __restrict__ Wr,
                       unsigned short* __restrict__ out, int Hreal, int NCT) {
    int tid = blockIdx.x * blockDim.x + threadIdx.x;
    int total = NCT * 8 * 64 * 8;
    if (tid >= total) return;
    int i = tid & 7;
    int lane = (tid >> 3) & 63;
    int q = tid >> 9;
    int c = q % NCT;
    int t = q / NCT;
    int k = t * 32 + (lane >> 4) * 8 + i;
    int n = c * 16 + (lane & 15);
    float v = 0.f;
    if (n < Hreal) v = (k < 128) ? Wl[k * Hreal + n] : Wr[(k - 128) * Hreal + n];
    out[tid] = f2b(v);
}

// ---------------- CSR build: two-level counting sort -------------------------
__global__ void __launch_bounds__(256) hist_k(const int* __restrict__ dst,
                                              unsigned int* __restrict__ cnt,
                                              unsigned int* __restrict__ bhist) {
    __shared__ unsigned int lh[8];
    if (threadIdx.x < 8) lh[threadIdx.x] = 0;
    __syncthreads();
    int start = blockIdx.x * HB_PER;
    for (int i = threadIdx.x; i < HB_PER; i += 256) {
        int d = dst[start + i];
        atomicAdd(&cnt[d], 1u);
        atomicAdd(&lh[(unsigned int)d / BUCKET_N], 1u);
    }
    __syncthreads();
    if (threadIdx.x < 8) bhist[threadIdx.x * HB_BLOCKS + blockIdx.x] = lh[threadIdx.x];
}

__global__ void bscan(unsigned int* __restrict__ A) {
    __shared__ unsigned int part[256];
    int t = threadIdx.x;
    unsigned int v[8];
    unsigned int s = 0;
#pragma unroll
    for (int i = 0; i < 8; i++) { v[i] = A[t * 8 + i]; s += v[i]; }
    part[t] = s; __syncthreads();
    for (int off = 1; off < 256; off <<= 1) {
        unsigned int add = (t >= off) ? part[t - off] : 0u;
        __syncthreads();
        part[t] += add;
        __syncthreads();
    }
    unsigned int base = part[t] - s;  // exclusive
#pragma unroll
    for (int i = 0; i < 8; i++) { unsigned int old = v[i]; A[t * 8 + i] = base; base += old; }
}

__global__ void __launch_bounds__(256) bscatter(const int* __restrict__ src,
                                                const int* __restrict__ dst,
                                                const unsigned int* __restrict__ boffs,
                                                unsigned int* __restrict__ ebuf) {
    __shared__ unsigned int cur[8];
    if (threadIdx.x < 8) cur[threadIdx.x] = boffs[threadIdx.x * HB_BLOCKS + blockIdx.x];
    __syncthreads();
    int start = blockIdx.x * HB_PER;
    for (int i = threadIdx.x; i < HB_PER; i += 256) {
        int d = dst[start + i];
        int s = src[start + i];
        unsigned int b = (unsigned int)d / BUCKET_N;
        unsigned int dl = (unsigned int)d - b * BUCKET_N;
        unsigned int pos = atomicAdd(&cur[b], 1u);
        ebuf[pos] = (unsigned int)s | (dl << 17);
    }
}

__global__ void __launch_bounds__(256) cscatter(const unsigned int* __restrict__ ebuf,
                                                const unsigned int* __restrict__ rowptr,
                                                unsigned int* __restrict__ cursor,
                                                int* __restrict__ srclist) {
    int g = blockIdx.x & 7;
    int gblk = blockIdx.x >> 3;
    unsigned int estart = rowptr[g * BUCKET_N];
    unsigned int eend = (g == 7) ? N_EDGES : rowptr[(g + 1) * BUCKET_N];
    unsigned int nume = eend - estart;
    unsigned int per = (nume + CS_GPB - 1) / CS_GPB;
    unsigned int s0 = estart + gblk * per;
    unsigned int s1 = s0 + per; if (s1 > eend) s1 = eend;
    unsigned int nodebase = g * BUCKET_N;
    for (unsigned int i = s0 + threadIdx.x; i < s1; i += 256) {
        unsigned int p = ebuf[i];
        unsigned int s = p & 0x1FFFFu;
        unsigned int node = nodebase + (p >> 17);
        unsigned int pos = atomicAdd(&cursor[node], 1u);
        srclist[pos] = (int)s;
    }
}

__global__ void scan1(const unsigned int* __restrict__ cnt, unsigned int* __restrict__ rowptr,
                      unsigned int* __restrict__ bsum) {
    __shared__ unsigned int sh[256];
    int t = threadIdx.x;
    int i = blockIdx.x * 256 + t;
    unsigned int v = (i < N_NODES) ? cnt[i] : 0u;
    sh[t] = v; __syncthreads();
    for (int off = 1; off < 256; off <<= 1) {
        unsigned int add = (t >= off) ? sh[t - off] : 0u;
        __syncthreads();
        sh[t] += add;
        __syncthreads();
    }
    if (i < N_NODES) rowptr[i] = sh[t] - v;  // exclusive within block
    if (t == 255) bsum[blockIdx.x] = sh[255];
}

__global__ void scan2(const unsigned int* __restrict__ bsum, unsigned int* __restrict__ boff, int nb) {
    __shared__ unsigned int sh[512];
    int t = threadIdx.x;
    unsigned int v = (t < nb) ? bsum[t] : 0u;
    sh[t] = v; __syncthreads();
    for (int off = 1; off < 512; off <<= 1) {
        unsigned int add = (t >= off) ? sh[t - off] : 0u;
        __syncthreads();
        sh[t] += add;
        __syncthreads();
    }
    if (t < nb) boff[t] = sh[t] - v;
}

__global__ void scan3(unsigned int* __restrict__ rowptr, const unsigned int* __restrict__ boff,
                      unsigned int* __restrict__ cursor) {
    int i = blockIdx.x * 256 + threadIdx.x;
    if (i < N_NODES) {
        unsigned int r = rowptr[i] + boff[blockIdx.x];
        rowptr[i] = r;
        cursor[i] = r;
    }
    if (i == N_NODES) rowptr[N_NODES] = N_EDGES;
}

// ---------------- phase-1 helper: aggregate NPG nodes/group into LDS ---------
// wave = 4 groups x 16 lanes; group handles NPG nodes sequentially; lane owns
// a 16 B row-slice. Unroll-4 gather: 4 independent row loads in flight
// (R8 post-mortem: 2-deep unroll at 6 blocks/CU starved MLP -> 1.95 TB/s).
template <int NPG>
__device__ __forceinline__ void agg_phase(const unsigned short* __restrict__ hb,
                                          const unsigned int* __restrict__ rowptr,
                                          const int* __restrict__ srclist,
                                          unsigned int* __restrict__ smean,
                                          int wave, int g, int l, int blockrow) {
    const uint4* hp = (const uint4*)hb;
#pragma unroll
    for (int it = 0; it < NPG; ++it) {
        int nl = wave * (4 * NPG) + it * 4 + g;
        int node = blockrow + nl;
        float f0 = 0.f, f1 = 0.f, f2 = 0.f, f3 = 0.f, f4 = 0.f, f5 = 0.f, f6 = 0.f, f7 = 0.f;
        if (node < N_NODES) {
            unsigned int b = rowptr[node], e = rowptr[node + 1];
            unsigned int p = b;
            for (; p + 4 <= e; p += 4) {
                int s0 = srclist[p];
                int s1 = srclist[p + 1];
                int s2 = srclist[p + 2];
                int s3 = srclist[p + 3];
                uint4 u0 = hp[(size_t)s0 * 16 + l];
                uint4 u1 = hp[(size_t)s1 * 16 + l];
                uint4 u2 = hp[(size_t)s2 * 16 + l];
                uint4 u3 = hp[(size_t)s3 * 16 + l];
                f0 += blo(u0.x); f1 += bhi(u0.x); f2 += blo(u0.y); f3 += bhi(u0.y);
                f4 += blo(u0.z); f5 += bhi(u0.z); f6 += blo(u0.w); f7 += bhi(u0.w);
                f0 += blo(u1.x); f1 += bhi(u1.x); f2 += blo(u1.y); f3 += bhi(u1.y);
                f4 += blo(u1.z); f5 += bhi(u1.z); f6 += blo(u1.w); f7 += bhi(u1.w);
                f0 += blo(u2.x); f1 += bhi(u2.x); f2 += blo(u2.y); f3 += bhi(u2.y);
                f4 += blo(u2.z); f5 += bhi(u2.z); f6 += blo(u2.w); f7 += bhi(u2.w);
                f0 += blo(u3.x); f1 += bhi(u3.x); f2 += blo(u3.y); f3 += bhi(u3.y);
                f4 += blo(u3.z); f5 += bhi(u3.z); f6 += blo(u3.w); f7 += bhi(u3.w);
            }
            if (p + 2 <= e) {
                int s0 = srclist[p];
                int s1 = srclist[p + 1];
                uint4 u0 = hp[(size_t)s0 * 16 + l];
                uint4 u1 = hp[(size_t)s1 * 16 + l];
                f0 += blo(u0.x); f1 += bhi(u0.x); f2 += blo(u0.y); f3 += bhi(u0.y);
                f4 += blo(u0.z); f5 += bhi(u0.z); f6 += blo(u0.w); f7 += bhi(u0.w);
                f0 += blo(u1.x); f1 += bhi(u1.x); f2 += blo(u1.y); f3 += bhi(u1.y);
                f4 += blo(u1.z); f5 += bhi(u1.z); f6 += blo(u1.w); f7 += bhi(u1.w);
                p += 2;
            }
            if (p < e) {
                int s0 = srclist[p];
                uint4 u0 = hp[(size_t)s0 * 16 + l];
                f0 += blo(u0.x); f1 += bhi(u0.x); f2 += blo(u0.y); f3 += bhi(u0.y);
                f4 += blo(u0.z); f5 += bhi(u0.z); f6 += blo(u0.w); f7 += bhi(u0.w);
            }
            unsigned int deg = e - b;
            float r = 1.0f / (float)(deg > 1u ? deg : 1u);
            f0 *= r; f1 *= r; f2 *= r; f3 *= r; f4 *= r; f5 *= r; f6 *= r; f7 *= r;
        }
        uint4 o;
        o.x = (unsigned int)f2b(f0) | ((unsigned int)f2b(f1) << 16);
        o.y = (unsigned int)f2b(f2) | ((unsigned int)f2b(f3) << 16);
        o.z = (unsigned int)f2b(f4) | ((unsigned int)f2b(f5) << 16);
        o.w = (unsigned int)f2b(f6) | ((unsigned int)f2b(f7) << 16);
        *(uint4*)&smean[nl * MROW + l * 4] = o;
    }
}

// ---------------- fused agg + GEMM L0/L1 + BN stats + bf16 C -----------------
// 32-row blocks (grid 3125 = 12.2 blocks/CU, 2x R8's residency); 4 waves =
// 2 row-slices x 2 col-halves of 16 rows.
__global__ void __launch_bounds__(256) gemm2f_k(const unsigned short* __restrict__ hb,
                                                const unsigned int* __restrict__ rowptr,
                                                const int* __restrict__ srclist,
                                                const unsigned short* __restrict__ Bp,
                                                unsigned short* __restrict__ outb,
                                                float* __restrict__ sums) {
    __shared__ unsigned int smean[32 * MROW];
    __shared__ float lds_s[128];
    __shared__ float lds_s2[128];
    int wave = threadIdx.x >> 6;
    int lane = threadIdx.x & 63;
    int quad = lane >> 4;
    int l15 = lane & 15;
    int blockrow = blockIdx.x * 32;

    if (threadIdx.x < 128) { lds_s[threadIdx.x] = 0.f; lds_s2[threadIdx.x] = 0.f; }

    // phase 1: aggregate 32 means into LDS (8 nodes/wave, 2/group)
    agg_phase<2>(hb, rowptr, srclist, smean, wave, quad, l15, blockrow);
    __syncthreads();

    // phase 2: 2 row-slices x 2 col-halves
    int rowslice = wave & 1;
    int colhalf = wave >> 1;
    int rowbase = blockrow + rowslice * 16;

    floatx4 acc[4];
#pragma unroll
    for (int c = 0; c < 4; c++) acc[c] = (floatx4){0.f, 0.f, 0.f, 0.f};

    int rl0 = rowslice * 16 + l15;
    int r0 = rowbase + l15;  if (r0 > N_NODES - 1) r0 = N_NODES - 1;

#pragma unroll
    for (int t = 0; t < 8; t++) {
        short8 a0;
        if (t < 4) {
            a0 = *(const short8*)&smean[rl0 * MROW + t * 16 + quad * 4];
        } else {
            int koff = (t & 3) * 32 + quad * 8;
            a0 = *(const short8*)(hb + (size_t)r0 * 128 + koff);
        }
#pragma unroll
        for (int c = 0; c < 4; c++) {
            int cidx = colhalf * 4 + c;
            short8 bf = *(const short8*)(Bp + ((size_t)(t * 8 + cidx) * 64 + lane) * 8);
            acc[c] = __builtin_amdgcn_mfma_f32_16x16x32_bf16(a0, bf, acc[c], 0, 0, 0);
        }
    }

#pragma unroll
    for (int c = 0; c < 4; c++) {
        int col = colhalf * 64 + c * 16 + l15;
        float s = 0.f, s2 = 0.f;
#pragma unroll
        for (int r = 0; r < 4; r++) {
            int row = rowbase + quad * 4 + r;
            if (row < N_NODES) {
                float v = acc[c][r];
                outb[(size_t)row * 128 + col] = f2b(v);
                s += v; s2 += v * v;
            }
        }
        s += __shfl_xor(s, 16);  s += __shfl_xor(s, 32);
        s2 += __shfl_xor(s2, 16); s2 += __shfl_xor(s2, 32);
        if (quad == 0) {
            atomicAdd(&lds_s[col], s);
            atomicAdd(&lds_s2[col], s2);
        }
    }

    __syncthreads();
    if (threadIdx.x < 128) {
        int bank = blockIdx.x & (NBANK - 1);
        atomicAdd(&sums[bank * 256 + threadIdx.x], lds_s[threadIdx.x]);
        atomicAdd(&sums[bank * 256 + 128 + threadIdx.x], lds_s2[threadIdx.x]);
    }
}

// ---------------- fused agg + GEMM L2 (40 cols, bias, fp32 out) --------------
// 64-row blocks, 4 waves = 4 row-slices of 16 rows; unroll-4 gather.
__global__ void __launch_bounds__(256) gemm3f_k(const unsigned short* __restrict__ hb,
                                                const unsigned int* __restrict__ rowptr,
                                                const int* __restrict__ srclist,
                                                const unsigned short* __restrict__ Bp,
                                                const float* __restrict__ bias,
                                                float* __restrict__ out) {
    __shared__ unsigned int smean[64 * MROW];
    int wave = threadIdx.x >> 6;
    int lane = threadIdx.x & 63;
    int quad = lane >> 4;
    int l15 = lane & 15;
    int blockrow = blockIdx.x * 64;

    agg_phase<4>(hb, rowptr, srclist, smean, wave, quad, l15, blockrow);
    __syncthreads();

    int rowbase = blockrow + wave * 16;
    floatx4 acc[3];
#pragma unroll
    for (int c = 0; c < 3; c++) acc[c] = (floatx4){0.f, 0.f, 0.f, 0.f};

    int rl0 = wave * 16 + l15;
    int r0 = rowbase + l15;  if (r0 > N_NODES - 1) r0 = N_NODES - 1;

#pragma unroll
    for (int t = 0; t < 8; t++) {
        short8 a0;
        if (t < 4) {
            a0 = *(const short8*)&smean[rl0 * MROW + t * 16 + quad * 4];
        } else {
            int koff = (t & 3) * 32 + quad * 8;
            a0 = *(const short8*)(hb + (size_t)r0 * 128 + koff);
        }
#pragma unroll
        for (int c = 0; c < 3; c++) {
            short8 bf = *(const short8*)(Bp + ((size_t)(t * 3 + c) * 64 + lane) * 8);
            acc[c] = __builtin_amdgcn_mfma_f32_16x16x32_bf16(a0, bf, acc[c], 0, 0, 0);
        }
    }

#pragma unroll
    for (int c = 0; c < 3; c++) {
        int col = c * 16 + l15;
        if (col >= 40) continue;
#pragma unroll
        for (int r = 0; r < 4; r++) {
            int row = rowbase + quad * 4 + r;
            if (row < N_NODES) out[(size_t)row * 40 + col] = acc[c][r] + bias[col];
        }
    }
}

// ---------------- BN finalize (reduce 32 banks) ------------------------------
__global__ void bn_finalize(const float* __restrict__ sums, const float* __restrict__ g,
                            const float* __restrict__ be, float* __restrict__ sc,
                            float* __restrict__ sh) {
    __shared__ float lds[256];
    int t = threadIdx.x;
    float s = 0.f;
#pragma unroll 8
    for (int bk = 0; bk < NBANK; bk++) s += sums[bk * 256 + t];
    lds[t] = s;
    __syncthreads();
    if (t < 128) {
        float inv_n = 1.0f / (float)N_NODES;
        float mu = lds[t] * inv_n;
        float var = lds[128 + t] * inv_n - mu * mu;
        float sf = g[t] * rsqrtf(var + EPS);
        sc[t] = sf;
        sh[t] = be[t] - mu * sf;
    }
}

// ---------------- BN apply: bf16 in -> bf16 out, 8 elems/thread --------------
__global__ void bn_apply(const unsigned int* __restrict__ Cb, const float* __restrict__ sc,
                         const float* __restrict__ sh, unsigned short* __restrict__ ho) {
    int i = blockIdx.x * 256 + threadIdx.x;  // one uint4 = 8 bf16
    if (i >= N_NODES * 16) return;
    uint4 v = ((const uint4*)Cb)[i];
    int c0 = (i * 8) & 127;
    uint4 o;
    float e0 = fmaxf(0.f, blo(v.x) * sc[c0 + 0] + sh[c0 + 0]);
    float e1 = fmaxf(0.f, bhi(v.x) * sc[c0 + 1] + sh[c0 + 1]);
    float e2 = fmaxf(0.f, blo(v.y) * sc[c0 + 2] + sh[c0 + 2]);
    float e3 = fmaxf(0.f, bhi(v.y) * sc[c0 + 3] + sh[c0 + 3]);
    float e4 = fmaxf(0.f, blo(v.z) * sc[c0 + 4] + sh[c0 + 4]);
    float e5 = fmaxf(0.f, bhi(v.z) * sc[c0 + 5] + sh[c0 + 5]);
    float e6 = fmaxf(0.f, blo(v.w) * sc[c0 + 6] + sh[c0 + 6]);
    float e7 = fmaxf(0.f, bhi(v.w) * sc[c0 + 7] + sh[c0 + 7]);
    o.x = (unsigned int)f2b(e0) | ((unsigned int)f2b(e1) << 16);
    o.y = (unsigned int)f2b(e2) | ((unsigned int)f2b(e3) << 16);
    o.z = (unsigned int)f2b(e4) | ((unsigned int)f2b(e5) << 16);
    o.w = (unsigned int)f2b(e6) | ((unsigned int)f2b(e7) << 16);
    ((uint4*)ho)[i] = o;
}

// ---------------- host ----------------
extern "C" void kernel_launch(void* const* d_in, const int* in_sizes, int n_in,
                              void* d_out, int out_size, void* d_ws, size_t ws_size,
                              hipStream_t stream) {
    const float* x   = (const float*)d_in[0];
    const int* ei    = (const int*)d_in[1];     // [2, E] int32: row 0 = src, row 1 = dst
    const float* Wl0 = (const float*)d_in[2];
    const float* Wr0 = (const float*)d_in[3];
    const float* Wl1 = (const float*)d_in[4];
    const float* Wr1 = (const float*)d_in[5];
    const float* Wl2 = (const float*)d_in[6];
    const float* Wr2 = (const float*)d_in[7];
    const float* b2  = (const float*)d_in[8];
    const float* g0  = (const float*)d_in[9];
    const float* be0 = (const float*)d_in[10];
    const float* g1  = (const float*)d_in[11];
    const float* be1 = (const float*)d_in[12];

    char* ws = (char*)d_ws;
    size_t off = 0;
    auto alloc = [&](size_t bytes) -> void* {
        void* p = ws + off;
        off += (bytes + 4095) & ~(size_t)4095;
        return p;
    };

    const size_t NB16 = (size_t)N_NODES * 128 * 2;  // 25.6 MB bf16 feature buffer
    unsigned short* xb   = (unsigned short*)alloc(NB16);   // x in bf16; reused as h2
    unsigned short* h1   = (unsigned short*)alloc(NB16);
    unsigned short* C    = (unsigned short*)alloc(NB16);   // pre-BN bf16
    unsigned int* cnt    = (unsigned int*)alloc((size_t)N_NODES * 4);
    unsigned int* rowptr = (unsigned int*)alloc((size_t)(N_NODES + 1) * 4);
    unsigned int* cursor = (unsigned int*)alloc((size_t)N_NODES * 4);
    int* srclist         = (int*)alloc((size_t)N_EDGES * 4);
    unsigned int* ebuf   = (unsigned int*)alloc((size_t)N_EDGES * 4);
    unsigned int* bhist  = (unsigned int*)alloc(8 * HB_BLOCKS * 4);
    unsigned int* bsum   = (unsigned int*)alloc(512 * 4);
    unsigned int* boff   = (unsigned int*)alloc(512 * 4);
    float* sums0         = (float*)alloc(NBANK * 256 * 4);   // contiguous with sums1
    float* sums1         = (float*)alloc(NBANK * 256 * 4);
    float* sc            = (float*)alloc(128 * 4);
    float* sh            = (float*)alloc(128 * 4);
    unsigned short* W0p  = (unsigned short*)alloc(8 * 8 * 64 * 8 * 2);
    unsigned short* W1p  = (unsigned short*)alloc(8 * 8 * 64 * 8 * 2);
    unsigned short* W2p  = (unsigned short*)alloc(3 * 8 * 64 * 8 * 2);
    unsigned short* h2   = xb;  // alias: xb dead after layer-0 GEMM

    const int* srcp = ei;
    const int* dstp = ei + N_EDGES;

    // ---- prep (both BN sums buffers zeroed up front; none mid-pipeline) ----
    hipMemsetAsync(cnt, 0, (size_t)N_NODES * 4, stream);
    hipMemsetAsync(sums0, 0, (size_t)2 * NBANK * 256 * 4, stream);  // sums0+sums1
    cvt_f32_bf16<<<12500, 256, 0, stream>>>(x, xb, N_NODES * 32);
    pack_w<<<(8 * 4096 + 255) / 256, 256, 0, stream>>>(Wl0, Wr0, W0p, 128, 8);
    pack_w<<<(8 * 4096 + 255) / 256, 256, 0, stream>>>(Wl1, Wr1, W1p, 128, 8);
    pack_w<<<(3 * 4096 + 255) / 256, 256, 0, stream>>>(Wl2, Wr2, W2p, 40, 3);

    // ---- CSR (two-level counting sort) ----
    hist_k<<<HB_BLOCKS, 256, 0, stream>>>(dstp, cnt, bhist);
    scan1<<<391, 256, 0, stream>>>(cnt, rowptr, bsum);
    scan2<<<1, 512, 0, stream>>>(bsum, boff, 391);
    scan3<<<391, 256, 0, stream>>>(rowptr, boff, cursor);
    bscan<<<1, 256, 0, stream>>>(bhist);
    bscatter<<<HB_BLOCKS, 256, 0, stream>>>(srcp, dstp, bhist, ebuf);
    cscatter<<<8 * CS_GPB, 256, 0, stream>>>(ebuf, rowptr, cursor, srclist);

    // ---- layer 0 (fused agg+gemm, 32-row blocks) ----
    gemm2f_k<<<3125, 256, 0, stream>>>(xb, rowptr, srclist, W0p, C, sums0);
    bn_finalize<<<1, 256, 0, stream>>>(sums0, g0, be0, sc, sh);
    bn_apply<<<6250, 256, 0, stream>>>((const unsigned int*)C, sc, sh, h1);

    // ---- layer 1 ----
    gemm2f_k<<<3125, 256, 0, stream>>>(h1, rowptr, srclist, W1p, C, sums1);
    bn_finalize<<<1, 256, 0, stream>>>(sums1, g1, be1, sc, sh);
    bn_apply<<<6250, 256, 0, stream>>>((const unsigned int*)C, sc, sh, h2);

    // ---- layer 2 (writes d_out, fp32 [N,40]) ----
    gemm3f_k<<<1563, 256, 0, stream>>>(h2, rowptr, srclist, W2p, b2, (float*)d_out);

    (void)in_sizes; (void)n_in; (void)out_size; (void)ws_size;
}

// Round 10
// 372.398 us; speedup vs baseline: 2.2138x; 1.0283x over previous
//
#include <hip/hip_runtime.h>
#include <hip/hip_bf16.h>

#define N_NODES 100000
#define N_EDGES 800000
#define EPS 1e-5f
#define NBANK 32
#define HB_BLOCKS 256
#define HB_PER 3125          // 256 * 3125 = 800000 exactly
#define CS_GPB 64            // cscatter blocks per coarse bucket
#define BUCKET_N 12500       // 8 * 12500 = 100000 exactly
#define MROW 68              // LDS mean row stride in dwords (64 + 4 pad)

typedef __attribute__((ext_vector_type(8))) short short8;
typedef __attribute__((ext_vector_type(4))) float floatx4;

__device__ __forceinline__ unsigned short f2b(float f) {
    unsigned int u = __float_as_uint(f);
    u = (u + 0x7fffu + ((u >> 16) & 1u)) >> 16;   // round-to-nearest-even
    return (unsigned short)u;
}
__device__ __forceinline__ float blo(unsigned int u) { return __uint_as_float(u << 16); }
__device__ __forceinline__ float bhi(unsigned int u) { return __uint_as_float(u & 0xffff0000u); }

// ---------------- elementwise convert fp32 -> bf16 (x input) ----------------
__global__ void cvt_f32_bf16(const float* __restrict__ x, unsigned short* __restrict__ o, int n4) {
    int i = blockIdx.x * blockDim.x + threadIdx.x;
    if (i >= n4) return;
    float4 v = ((const float4*)x)[i];
    ushort4 r;
    r.x = f2b(v.x); r.y = f2b(v.y); r.z = f2b(v.z); r.w = f2b(v.w);
    ((ushort4*)o)[i] = r;
}

// ---------------- pack [Wl;Wr] (K=256 x Hreal) into MFMA B-fragment order ----
__global__ void pack_w(const float* __restrict__ Wl, const float* __restrict__ Wr,
                       unsigned short* __restrict__ out, int Hreal, int NCT) {
    int tid = blockIdx.x * blockDim.x + threadIdx.x;
    int total = NCT * 8 * 64 * 8;
    if (tid >= total) return;
    int i = tid & 7;
    int lane = (tid >> 3) & 63;
    int q = tid >> 9;
    int c = q % NCT;
    int t = q / NCT;
    int k = t * 32 + (lane >> 4) * 8 + i;
    int n = c * 16 + (lane & 15);
    float v = 0.f;
    if (n < Hreal) v = (k < 128) ? Wl[k * Hreal + n] : Wr[(k - 128) * Hreal + n];
    out[tid] = f2b(v);
}

// ---------------- CSR build: two-level counting sort -------------------------
__global__ void __launch_bounds__(256) hist_k(const int* __restrict__ dst,
                                              unsigned int* __restrict__ cnt,
                                              unsigned int* __restrict__ bhist) {
    __shared__ unsigned int lh[8];
    if (threadIdx.x < 8) lh[threadIdx.x] = 0;
    __syncthreads();
    int start = blockIdx.x * HB_PER;
    for (int i = threadIdx.x; i < HB_PER; i += 256) {
        int d = dst[start + i];
        atomicAdd(&cnt[d], 1u);
        atomicAdd(&lh[(unsigned int)d / BUCKET_N], 1u);
    }
    __syncthreads();
    if (threadIdx.x < 8) bhist[threadIdx.x * HB_BLOCKS + blockIdx.x] = lh[threadIdx.x];
}

__global__ void bscan(unsigned int* __restrict__ A) {
    __shared__ unsigned int part[256];
    int t = threadIdx.x;
    unsigned int v[8];
    unsigned int s = 0;
#pragma unroll
    for (int i = 0; i < 8; i++) { v[i] = A[t * 8 + i]; s += v[i]; }
    part[t] = s; __syncthreads();
    for (int off = 1; off < 256; off <<= 1) {
        unsigned int add = (t >= off) ? part[t - off] : 0u;
        __syncthreads();
        part[t] += add;
        __syncthreads();
    }
    unsigned int base = part[t] - s;  // exclusive
#pragma unroll
    for (int i = 0; i < 8; i++) { unsigned int old = v[i]; A[t * 8 + i] = base; base += old; }
}

__global__ void __launch_bounds__(256) bscatter(const int* __restrict__ src,
                                                const int* __restrict__ dst,
                                                const unsigned int* __restrict__ boffs,
                                                unsigned int* __restrict__ ebuf) {
    __shared__ unsigned int cur[8];
    if (threadIdx.x < 8) cur[threadIdx.x] = boffs[threadIdx.x * HB_BLOCKS + blockIdx.x];
    __syncthreads();
    int start = blockIdx.x * HB_PER;
    for (int i = threadIdx.x; i < HB_PER; i += 256) {
        int d = dst[start + i];
        int s = src[start + i];
        unsigned int b = (unsigned int)d / BUCKET_N;
        unsigned int dl = (unsigned int)d - b * BUCKET_N;
        unsigned int pos = atomicAdd(&cur[b], 1u);
        ebuf[pos] = (unsigned int)s | (dl << 17);
    }
}

__global__ void __launch_bounds__(256) cscatter(const unsigned int* __restrict__ ebuf,
                                                const unsigned int* __restrict__ rowptr,
                                                unsigned int* __restrict__ cursor,
                                                int* __restrict__ srclist) {
    int g = blockIdx.x & 7;
    int gblk = blockIdx.x >> 3;
    unsigned int estart = rowptr[g * BUCKET_N];
    unsigned int eend = (g == 7) ? N_EDGES : rowptr[(g + 1) * BUCKET_N];
    unsigned int nume = eend - estart;
    unsigned int per = (nume + CS_GPB - 1) / CS_GPB;
    unsigned int s0 = estart + gblk * per;
    unsigned int s1 = s0 + per; if (s1 > eend) s1 = eend;
    unsigned int nodebase = g * BUCKET_N;
    for (unsigned int i = s0 + threadIdx.x; i < s1; i += 256) {
        unsigned int p = ebuf[i];
        unsigned int s = p & 0x1FFFFu;
        unsigned int node = nodebase + (p >> 17);
        unsigned int pos = atomicAdd(&cursor[node], 1u);
        srclist[pos] = (int)s;
    }
}

__global__ void scan1(const unsigned int* __restrict__ cnt, unsigned int* __restrict__ rowptr,
                      unsigned int* __restrict__ bsum) {
    __shared__ unsigned int sh[256];
    int t = threadIdx.x;
    int i = blockIdx.x * 256 + t;
    unsigned int v = (i < N_NODES) ? cnt[i] : 0u;
    sh[t] = v; __syncthreads();
    for (int off = 1; off < 256; off <<= 1) {
        unsigned int add = (t >= off) ? sh[t - off] : 0u;
        __syncthreads();
        sh[t] += add;
        __syncthreads();
    }
    if (i < N_NODES) rowptr[i] = sh[t] - v;  // exclusive within block
    if (t == 255) bsum[blockIdx.x] = sh[255];
}

__global__ void scan2(const unsigned int* __restrict__ bsum, unsigned int* __restrict__ boff, int nb) {
    __shared__ unsigned int sh[512];
    int t = threadIdx.x;
    unsigned int v = (t < nb) ? bsum[t] : 0u;
    sh[t] = v; __syncthreads();
    for (int off = 1; off < 512; off <<= 1) {
        unsigned int add = (t >= off) ? sh[t - off] : 0u;
        __syncthreads();
        sh[t] += add;
        __syncthreads();
    }
    if (t < nb) boff[t] = sh[t] - v;
}

__global__ void scan3(unsigned int* __restrict__ rowptr, const unsigned int* __restrict__ boff,
                      unsigned int* __restrict__ cursor) {
    int i = blockIdx.x * 256 + threadIdx.x;
    if (i < N_NODES) {
        unsigned int r = rowptr[i] + boff[blockIdx.x];
        rowptr[i] = r;
        cursor[i] = r;
    }
    if (i == N_NODES) rowptr[N_NODES] = N_EDGES;
}

// ---------------- phase-1: aggregate 16 nodes into LDS, 1 node/group ---------
// (R9 post-mortem: 32-row tile = 2 serial nodes/group + wave-capped occupancy.
//  16-row tile: 16 groups <-> 16 nodes fully parallel, unroll-4 = 16 edges in
//  flight per wave.)
__device__ __forceinline__ void agg_phase16(const unsigned short* __restrict__ hb,
                                            const unsigned int* __restrict__ rowptr,
                                            const int* __restrict__ srclist,
                                            unsigned int* __restrict__ smean,
                                            int wave, int g, int l, int blockrow) {
    const uint4* hp = (const uint4*)hb;
    int nl = wave * 4 + g;
    int node = blockrow + nl;   // grid is N/16 exactly -> always < N_NODES
    float f0 = 0.f, f1 = 0.f, f2 = 0.f, f3 = 0.f, f4 = 0.f, f5 = 0.f, f6 = 0.f, f7 = 0.f;
    unsigned int b = rowptr[node], e = rowptr[node + 1];
    unsigned int p = b;
    for (; p + 4 <= e; p += 4) {
        int s0 = srclist[p];
        int s1 = srclist[p + 1];
        int s2 = srclist[p + 2];
        int s3 = srclist[p + 3];
        uint4 u0 = hp[(size_t)s0 * 16 + l];
        uint4 u1 = hp[(size_t)s1 * 16 + l];
        uint4 u2 = hp[(size_t)s2 * 16 + l];
        uint4 u3 = hp[(size_t)s3 * 16 + l];
        f0 += blo(u0.x); f1 += bhi(u0.x); f2 += blo(u0.y); f3 += bhi(u0.y);
        f4 += blo(u0.z); f5 += bhi(u0.z); f6 += blo(u0.w); f7 += bhi(u0.w);
        f0 += blo(u1.x); f1 += bhi(u1.x); f2 += blo(u1.y); f3 += bhi(u1.y);
        f4 += blo(u1.z); f5 += bhi(u1.z); f6 += blo(u1.w); f7 += bhi(u1.w);
        f0 += blo(u2.x); f1 += bhi(u2.x); f2 += blo(u2.y); f3 += bhi(u2.y);
        f4 += blo(u2.z); f5 += bhi(u2.z); f6 += blo(u2.w); f7 += bhi(u2.w);
        f0 += blo(u3.x); f1 += bhi(u3.x); f2 += blo(u3.y); f3 += bhi(u3.y);
        f4 += blo(u3.z); f5 += bhi(u3.z); f6 += blo(u3.w); f7 += bhi(u3.w);
    }
    if (p + 2 <= e) {
        int s0 = srclist[p];
        int s1 = srclist[p + 1];
        uint4 u0 = hp[(size_t)s0 * 16 + l];
        uint4 u1 = hp[(size_t)s1 * 16 + l];
        f0 += blo(u0.x); f1 += bhi(u0.x); f2 += blo(u0.y); f3 += bhi(u0.y);
        f4 += blo(u0.z); f5 += bhi(u0.z); f6 += blo(u0.w); f7 += bhi(u0.w);
        f0 += blo(u1.x); f1 += bhi(u1.x); f2 += blo(u1.y); f3 += bhi(u1.y);
        f4 += blo(u1.z); f5 += bhi(u1.z); f6 += blo(u1.w); f7 += bhi(u1.w);
        p += 2;
    }
    if (p < e) {
        int s0 = srclist[p];
        uint4 u0 = hp[(size_t)s0 * 16 + l];
        f0 += blo(u0.x); f1 += bhi(u0.x); f2 += blo(u0.y); f3 += bhi(u0.y);
        f4 += blo(u0.z); f5 += bhi(u0.z); f6 += blo(u0.w); f7 += bhi(u0.w);
    }
    unsigned int deg = e - b;
    float r = 1.0f / (float)(deg > 1u ? deg : 1u);
    uint4 o;
    o.x = (unsigned int)f2b(f0 * r) | ((unsigned int)f2b(f1 * r) << 16);
    o.y = (unsigned int)f2b(f2 * r) | ((unsigned int)f2b(f3 * r) << 16);
    o.z = (unsigned int)f2b(f4 * r) | ((unsigned int)f2b(f5 * r) << 16);
    o.w = (unsigned int)f2b(f6 * r) | ((unsigned int)f2b(f7 * r) << 16);
    *(uint4*)&smean[nl * MROW + l * 4] = o;
}

// ---------------- fused agg + GEMM L0/L1 + BN stats + bf16 C -----------------
// 16-row blocks, grid 6250 (= N/16). Phase 2: wave w handles cols [32w,32w+32)
// of all 16 rows (acc = 8 VGPRs).
__global__ void __launch_bounds__(256) gemm2f_k(const unsigned short* __restrict__ hb,
                                                const unsigned int* __restrict__ rowptr,
                                                const int* __restrict__ srclist,
                                                const unsigned short* __restrict__ Bp,
                                                unsigned short* __restrict__ outb,
                                                float* __restrict__ sums) {
    __shared__ unsigned int smean[16 * MROW];
    __shared__ float lds_s[128];
    __shared__ float lds_s2[128];
    int wave = threadIdx.x >> 6;
    int lane = threadIdx.x & 63;
    int quad = lane >> 4;
    int l15 = lane & 15;
    int blockrow = blockIdx.x * 16;

    if (threadIdx.x < 128) { lds_s[threadIdx.x] = 0.f; lds_s2[threadIdx.x] = 0.f; }

    agg_phase16(hb, rowptr, srclist, smean, wave, quad, l15, blockrow);
    __syncthreads();

    floatx4 acc[2];
    acc[0] = (floatx4){0.f, 0.f, 0.f, 0.f};
    acc[1] = (floatx4){0.f, 0.f, 0.f, 0.f};

    int r0 = blockrow + l15;   // always < N_NODES (exact division)

#pragma unroll
    for (int t = 0; t < 8; t++) {
        short8 a0;
        if (t < 4) {
            a0 = *(const short8*)&smean[l15 * MROW + t * 16 + quad * 4];
        } else {
            int koff = (t & 3) * 32 + quad * 8;
            a0 = *(const short8*)(hb + (size_t)r0 * 128 + koff);
        }
#pragma unroll
        for (int c = 0; c < 2; c++) {
            int cidx = wave * 2 + c;
            short8 bf = *(const short8*)(Bp + ((size_t)(t * 8 + cidx) * 64 + lane) * 8);
            acc[c] = __builtin_amdgcn_mfma_f32_16x16x32_bf16(a0, bf, acc[c], 0, 0, 0);
        }
    }

#pragma unroll
    for (int c = 0; c < 2; c++) {
        int col = wave * 32 + c * 16 + l15;
        float s = 0.f, s2 = 0.f;
#pragma unroll
        for (int r = 0; r < 4; r++) {
            int row = blockrow + quad * 4 + r;
            float v = acc[c][r];
            outb[(size_t)row * 128 + col] = f2b(v);
            s += v; s2 += v * v;
        }
        s += __shfl_xor(s, 16);  s += __shfl_xor(s, 32);
        s2 += __shfl_xor(s2, 16); s2 += __shfl_xor(s2, 32);
        if (quad == 0) {
            atomicAdd(&lds_s[col], s);
            atomicAdd(&lds_s2[col], s2);
        }
    }

    __syncthreads();
    if (threadIdx.x < 128) {
        int bank = blockIdx.x & (NBANK - 1);
        atomicAdd(&sums[bank * 256 + threadIdx.x], lds_s[threadIdx.x]);
        atomicAdd(&sums[bank * 256 + 128 + threadIdx.x], lds_s2[threadIdx.x]);
    }
}

// ---------------- fused agg + GEMM L2 (40 cols, bias, fp32 out) --------------
// 16-row blocks; waves 0-2 each own one 16-col tile (48 >= 40); wave 3 only
// helps in the gather phase.
__global__ void __launch_bounds__(256) gemm3f_k(const unsigned short* __restrict__ hb,
                                                const unsigned int* __restrict__ rowptr,
                                                const int* __restrict__ srclist,
                                                const unsigned short* __restrict__ Bp,
                                                const float* __restrict__ bias,
                                                float* __restrict__ out) {
    __shared__ unsigned int smean[16 * MROW];
    int wave = threadIdx.x >> 6;
    int lane = threadIdx.x & 63;
    int quad = lane >> 4;
    int l15 = lane & 15;
    int blockrow = blockIdx.x * 16;

    agg_phase16(hb, rowptr, srclist, smean, wave, quad, l15, blockrow);
    __syncthreads();

    if (wave >= 3) return;

    floatx4 acc = (floatx4){0.f, 0.f, 0.f, 0.f};
    int r0 = blockrow + l15;

#pragma unroll
    for (int t = 0; t < 8; t++) {
        short8 a0;
        if (t < 4) {
            a0 = *(const short8*)&smean[l15 * MROW + t * 16 + quad * 4];
        } else {
            int koff = (t & 3) * 32 + quad * 8;
            a0 = *(const short8*)(hb + (size_t)r0 * 128 + koff);
        }
        short8 bf = *(const short8*)(Bp + ((size_t)(t * 3 + wave) * 64 + lane) * 8);
        acc = __builtin_amdgcn_mfma_f32_16x16x32_bf16(a0, bf, acc, 0, 0, 0);
    }

    int col = wave * 16 + l15;
    if (col < 40) {
#pragma unroll
        for (int r = 0; r < 4; r++) {
            int row = blockrow + quad * 4 + r;
            out[(size_t)row * 40 + col] = acc[r] + bias[col];
        }
    }
}

// ---------------- BN finalize (reduce 32 banks) ------------------------------
__global__ void bn_finalize(const float* __restrict__ sums, const float* __restrict__ g,
                            const float* __restrict__ be, float* __restrict__ sc,
                            float* __restrict__ sh) {
    __shared__ float lds[256];
    int t = threadIdx.x;
    float s = 0.f;
#pragma unroll 8
    for (int bk = 0; bk < NBANK; bk++) s += sums[bk * 256 + t];
    lds[t] = s;
    __syncthreads();
    if (t < 128) {
        float inv_n = 1.0f / (float)N_NODES;
        float mu = lds[t] * inv_n;
        float var = lds[128 + t] * inv_n - mu * mu;
        float sf = g[t] * rsqrtf(var + EPS);
        sc[t] = sf;
        sh[t] = be[t] - mu * sf;
    }
}

// ---------------- BN apply: bf16 in -> bf16 out, 8 elems/thread --------------
__global__ void bn_apply(const unsigned int* __restrict__ Cb, const float* __restrict__ sc,
                         const float* __restrict__ sh, unsigned short* __restrict__ ho) {
    int i = blockIdx.x * 256 + threadIdx.x;  // one uint4 = 8 bf16
    if (i >= N_NODES * 16) return;
    uint4 v = ((const uint4*)Cb)[i];
    int c0 = (i * 8) & 127;
    uint4 o;
    float e0 = fmaxf(0.f, blo(v.x) * sc[c0 + 0] + sh[c0 + 0]);
    float e1 = fmaxf(0.f, bhi(v.x) * sc[c0 + 1] + sh[c0 + 1]);
    float e2 = fmaxf(0.f, blo(v.y) * sc[c0 + 2] + sh[c0 + 2]);
    float e3 = fmaxf(0.f, bhi(v.y) * sc[c0 + 3] + sh[c0 + 3]);
    float e4 = fmaxf(0.f, blo(v.z) * sc[c0 + 4] + sh[c0 + 4]);
    float e5 = fmaxf(0.f, bhi(v.z) * sc[c0 + 5] + sh[c0 + 5]);
    float e6 = fmaxf(0.f, blo(v.w) * sc[c0 + 6] + sh[c0 + 6]);
    float e7 = fmaxf(0.f, bhi(v.w) * sc[c0 + 7] + sh[c0 + 7]);
    o.x = (unsigned int)f2b(e0) | ((unsigned int)f2b(e1) << 16);
    o.y = (unsigned int)f2b(e2) | ((unsigned int)f2b(e3) << 16);
    o.z = (unsigned int)f2b(e4) | ((unsigned int)f2b(e5) << 16);
    o.w = (unsigned int)f2b(e6) | ((unsigned int)f2b(e7) << 16);
    ((uint4*)ho)[i] = o;
}

// ---------------- host ----------------
extern "C" void kernel_launch(void* const* d_in, const int* in_sizes, int n_in,
                              void* d_out, int out_size, void* d_ws, size_t ws_size,
                              hipStream_t stream) {
    const float* x   = (const float*)d_in[0];
    const int* ei    = (const int*)d_in[1];     // [2, E] int32: row 0 = src, row 1 = dst
    const float* Wl0 = (const float*)d_in[2];
    const float* Wr0 = (const float*)d_in[3];
    const float* Wl1 = (const float*)d_in[4];
    const float* Wr1 = (const float*)d_in[5];
    const float* Wl2 = (const float*)d_in[6];
    const float* Wr2 = (const float*)d_in[7];
    const float* b2  = (const float*)d_in[8];
    const float* g0  = (const float*)d_in[9];
    const float* be0 = (const float*)d_in[10];
    const float* g1  = (const float*)d_in[11];
    const float* be1 = (const float*)d_in[12];

    char* ws = (char*)d_ws;
    size_t off = 0;
    auto alloc = [&](size_t bytes) -> void* {
        void* p = ws + off;
        off += (bytes + 4095) & ~(size_t)4095;
        return p;
    };

    const size_t NB16 = (size_t)N_NODES * 128 * 2;  // 25.6 MB bf16 feature buffer
    unsigned short* xb   = (unsigned short*)alloc(NB16);   // x in bf16; reused as h2
    unsigned short* h1   = (unsigned short*)alloc(NB16);
    unsigned short* C    = (unsigned short*)alloc(NB16);   // pre-BN bf16
    unsigned int* cnt    = (unsigned int*)alloc((size_t)N_NODES * 4);
    unsigned int* rowptr = (unsigned int*)alloc((size_t)(N_NODES + 1) * 4);
    unsigned int* cursor = (unsigned int*)alloc((size_t)N_NODES * 4);
    int* srclist         = (int*)alloc((size_t)N_EDGES * 4);
    unsigned int* ebuf   = (unsigned int*)alloc((size_t)N_EDGES * 4);
    unsigned int* bhist  = (unsigned int*)alloc(8 * HB_BLOCKS * 4);
    unsigned int* bsum   = (unsigned int*)alloc(512 * 4);
    unsigned int* boff   = (unsigned int*)alloc(512 * 4);
    float* sums0         = (float*)alloc(NBANK * 256 * 4);   // contiguous with sums1
    float* sums1         = (float*)alloc(NBANK * 256 * 4);
    float* sc            = (float*)alloc(128 * 4);
    float* sh            = (float*)alloc(128 * 4);
    unsigned short* W0p  = (unsigned short*)alloc(8 * 8 * 64 * 8 * 2);
    unsigned short* W1p  = (unsigned short*)alloc(8 * 8 * 64 * 8 * 2);
    unsigned short* W2p  = (unsigned short*)alloc(3 * 8 * 64 * 8 * 2);
    unsigned short* h2   = xb;  // alias: xb dead after layer-0 GEMM

    const int* srcp = ei;
    const int* dstp = ei + N_EDGES;

    // ---- prep (both BN sums buffers zeroed up front; none mid-pipeline) ----
    hipMemsetAsync(cnt, 0, (size_t)N_NODES * 4, stream);
    hipMemsetAsync(sums0, 0, (size_t)2 * NBANK * 256 * 4, stream);  // sums0+sums1
    cvt_f32_bf16<<<12500, 256, 0, stream>>>(x, xb, N_NODES * 32);
    pack_w<<<(8 * 4096 + 255) / 256, 256, 0, stream>>>(Wl0, Wr0, W0p, 128, 8);
    pack_w<<<(8 * 4096 + 255) / 256, 256, 0, stream>>>(Wl1, Wr1, W1p, 128, 8);
    pack_w<<<(3 * 4096 + 255) / 256, 256, 0, stream>>>(Wl2, Wr2, W2p, 40, 3);

    // ---- CSR (two-level counting sort) ----
    hist_k<<<HB_BLOCKS, 256, 0, stream>>>(dstp, cnt, bhist);
    scan1<<<391, 256, 0, stream>>>(cnt, rowptr, bsum);
    scan2<<<1, 512, 0, stream>>>(bsum, boff, 391);
    scan3<<<391, 256, 0, stream>>>(rowptr, boff, cursor);
    bscan<<<1, 256, 0, stream>>>(bhist);
    bscatter<<<HB_BLOCKS, 256, 0, stream>>>(srcp, dstp, bhist, ebuf);
    cscatter<<<8 * CS_GPB, 256, 0, stream>>>(ebuf, rowptr, cursor, srclist);

    // ---- layer 0 (fused agg+gemm, 16-row blocks) ----
    gemm2f_k<<<6250, 256, 0, stream>>>(xb, rowptr, srclist, W0p, C, sums0);
    bn_finalize<<<1, 256, 0, stream>>>(sums0, g0, be0, sc, sh);
    bn_apply<<<6250, 256, 0, stream>>>((const unsigned int*)C, sc, sh, h1);

    // ---- layer 1 ----
    gemm2f_k<<<6250, 256, 0, stream>>>(h1, rowptr, srclist, W1p, C, sums1);
    bn_finalize<<<1, 256, 0, stream>>>(sums1, g1, be1, sc, sh);
    bn_apply<<<6250, 256, 0, stream>>>((const unsigned int*)C, sc, sh, h2);

    // ---- layer 2 (writes d_out, fp32 [N,40]) ----
    gemm3f_k<<<6250, 256, 0, stream>>>(h2, rowptr, srclist, W2p, b2, (float*)d_out);

    (void)in_sizes; (void)n_in; (void)out_size; (void)ws_size;
}